// Round 20
// baseline (1354.679 us; speedup 1.0000x reference)
//
#include <hip/hip_runtime.h>
#include <hip/hip_bf16.h>
#include <math.h>

#define TT 2048
#define BB 2
#define VV 32000
#define DD 512
#define HH 8
#define HSS 64
#define LL 4
#define FF_ 2048
#define NBLK_V (VV / 128)   // 250

using bf16x8 = __attribute__((ext_vector_type(8))) short;
using floatx4 = __attribute__((ext_vector_type(4))) float;

__device__ __forceinline__ ushort f2bf(float f) {
    __hip_bfloat16 b = __float2bfloat16(f);
    return *reinterpret_cast<ushort*>(&b);
}
__device__ __forceinline__ float bf2f(ushort u) {
    union { unsigned int i; float f; } x; x.i = ((unsigned int)u) << 16; return x.f;
}
__device__ __forceinline__ void gload16(const void* g, void* l) {
    __builtin_amdgcn_global_load_lds(
        (const __attribute__((address_space(1))) void*)g,
        (__attribute__((address_space(3))) void*)l, 16, 0, 0);
}

// ---------------- embedding
__global__ __launch_bounds__(64)
void embed_kernel(const int* __restrict__ idx, const float* __restrict__ tok,
                  const float* __restrict__ pos, float* __restrict__ x)
{
    int row = blockIdx.x;
    int t = row & (TT - 1);
    int tokid = idx[row];
    int lane = threadIdx.x;
    const float4* tp = (const float4*)(tok + (size_t)tokid * DD);
    const float4* pp = (const float4*)(pos + (size_t)t * DD);
    float4* xp = (float4*)(x + (size_t)row * DD);
    int i0 = lane * 2;
    float4 a = tp[i0],   b4 = pp[i0];
    float4 c = tp[i0+1], d4 = pp[i0+1];
    xp[i0]   = make_float4(a.x + b4.x, a.y + b4.y, a.z + b4.z, a.w + b4.w);
    xp[i0+1] = make_float4(c.x + d4.x, c.y + d4.y, c.z + d4.z, c.w + d4.w);
}

// ---------------- layernorm -> bf16
__global__ __launch_bounds__(256)
void ln_kernel(const float* __restrict__ x, const float* __restrict__ g,
               const float* __restrict__ b, ushort* __restrict__ out)
{
    int wave = threadIdx.x >> 6;
    int lane = threadIdx.x & 63;
    int row  = blockIdx.x * 4 + wave;
    const float* xr = x + (size_t)row * DD;
    float4 v0 = *(const float4*)(xr + lane * 8);
    float4 v1 = *(const float4*)(xr + lane * 8 + 4);
    float s = v0.x + v0.y + v0.z + v0.w + v1.x + v1.y + v1.z + v1.w;
    float q = v0.x*v0.x + v0.y*v0.y + v0.z*v0.z + v0.w*v0.w
            + v1.x*v1.x + v1.y*v1.y + v1.z*v1.z + v1.w*v1.w;
    #pragma unroll
    for (int off = 32; off; off >>= 1) {
        s += __shfl_xor(s, off);
        q += __shfl_xor(q, off);
    }
    float mu  = s * (1.0f / DD);
    float var = q * (1.0f / DD) - mu * mu;
    float rs  = rsqrtf(var + 1e-5f);
    float4 g0 = *(const float4*)(g + lane * 8);
    float4 g1 = *(const float4*)(g + lane * 8 + 4);
    float4 b0 = *(const float4*)(b + lane * 8);
    float4 b1 = *(const float4*)(b + lane * 8 + 4);
    union { ushort u[8]; uint4 v; } pk;
    pk.u[0] = f2bf((v0.x - mu) * rs * g0.x + b0.x);
    pk.u[1] = f2bf((v0.y - mu) * rs * g0.y + b0.y);
    pk.u[2] = f2bf((v0.z - mu) * rs * g0.z + b0.z);
    pk.u[3] = f2bf((v0.w - mu) * rs * g0.w + b0.w);
    pk.u[4] = f2bf((v1.x - mu) * rs * g1.x + b1.x);
    pk.u[5] = f2bf((v1.y - mu) * rs * g1.y + b1.y);
    pk.u[6] = f2bf((v1.z - mu) * rs * g1.z + b1.z);
    pk.u[7] = f2bf((v1.w - mu) * rs * g1.w + b1.w);
    *(uint4*)(out + (size_t)row * DD + lane * 8) = pk.v;
}

// ---------------- transpose+convert: in [K][N] f32 -> out [N][K] bf16
__global__ __launch_bounds__(256)
void transpose_cvt(const float* __restrict__ in, ushort* __restrict__ out,
                   int N, int K, long inStrideZ, long outStrideZ)
{
    __shared__ float t[64][65];
    in  += (size_t)blockIdx.z * inStrideZ;
    out += (size_t)blockIdx.z * outStrideZ;
    const int n0 = blockIdx.x * 64, k0 = blockIdx.y * 64;
    const int r = threadIdx.x >> 2;
    const int c = (threadIdx.x & 3) * 16;
    #pragma unroll
    for (int j = 0; j < 16; j += 4) {
        float4 v = *(const float4*)&in[(size_t)(k0 + r) * N + n0 + c + j];
        t[r][c + j + 0] = v.x; t[r][c + j + 1] = v.y;
        t[r][c + j + 2] = v.z; t[r][c + j + 3] = v.w;
    }
    __syncthreads();
    union { ushort u[8]; uint4 v; } pk;
    ushort* orow = out + (size_t)(n0 + r) * K + k0 + c;
    #pragma unroll
    for (int half = 0; half < 2; ++half) {
        #pragma unroll
        for (int j = 0; j < 8; ++j) pk.u[j] = f2bf(t[c + half * 8 + j][r]);
        *(uint4*)(orow + half * 8) = pk.v;
    }
}

// ---------------- QKV weights -> fused [L][1536][512] bf16
__global__ __launch_bounds__(256)
void qkv_transpose(const float* __restrict__ Wq, const float* __restrict__ Wk,
                   const float* __restrict__ Wv, ushort* __restrict__ out)
{
    __shared__ float t[64][65];
    const int z = blockIdx.y;
    const int sel = z >> 5, l = (z >> 3) & 3, h = z & 7;
    const float* in = (sel == 0 ? Wq : sel == 1 ? Wk : Wv)
                      + (size_t)l * (HH * DD * HSS) + (size_t)h * (DD * HSS);
    ushort* ob = out + (size_t)l * (3 * DD * DD) + (size_t)sel * (DD * DD)
                     + (size_t)h * (HSS * DD);
    const int d0 = blockIdx.x * 64;
    const int r = threadIdx.x >> 2;
    const int c = (threadIdx.x & 3) * 16;
    #pragma unroll
    for (int j = 0; j < 16; j += 4) {
        float4 v = *(const float4*)&in[(size_t)(d0 + r) * HSS + c + j];
        t[r][c + j + 0] = v.x; t[r][c + j + 1] = v.y;
        t[r][c + j + 2] = v.z; t[r][c + j + 3] = v.w;
    }
    __syncthreads();
    union { ushort u[8]; uint4 v; } pk;
    ushort* orow = ob + (size_t)r * DD + d0 + c;
    #pragma unroll
    for (int half = 0; half < 2; ++half) {
        #pragma unroll
        for (int j = 0; j < 8; ++j) pk.u[j] = f2bf(t[c + half * 8 + j][r]);
        *(uint4*)(orow + half * 8) = pk.v;
    }
}

// ---------------- V -> vt[bh][d][T] bf16 (per-layer, 4.2 MB)
__global__ __launch_bounds__(256)
void v_transpose(const ushort* __restrict__ qkv, ushort* __restrict__ vt)
{
    __shared__ ushort t[64][72];
    const int z = blockIdx.y;            // b*H + h
    const int t0 = blockIdx.x * 64;
    const int b = z >> 3, h = z & 7;
    const int tr = threadIdx.x >> 2;
    const int dc = (threadIdx.x & 3) * 16;
    const ushort* src = qkv + ((size_t)(b * TT + t0 + tr)) * 1536 + 1024 + h * HSS + dc;
    *(uint4*)&t[tr][dc]     = *(const uint4*)src;
    *(uint4*)&t[tr][dc + 8] = *(const uint4*)(src + 8);
    __syncthreads();
    const int dr = threadIdx.x >> 2;
    const int tc = (threadIdx.x & 3) * 16;
    ushort* dst = vt + ((size_t)z * 64 + dr) * TT + t0 + tc;
    union { ushort u[8]; uint4 v; } p0, p1;
    #pragma unroll
    for (int j = 0; j < 8; ++j) { p0.u[j] = t[tc + j][dr]; p1.u[j] = t[tc + 8 + j][dr]; }
    *(uint4*)dst       = p0.v;
    *(uint4*)(dst + 8) = p1.v;
}

// ---------------- logits GEMM: BM=512 x BN=128, BK=32, single-buffer
// 512 thr / 8 waves (4x2), wave owns 128x64 (acc[8][4]); halves B-sweeps
// to 8 (vs 16 at BM=256). LDS 48 KB -> 2 blocks/CU. A-fragments loaded
// one-at-a-time in the mi-loop to cap VGPR (~180 < 256 cap of (512,2)).
__global__ __launch_bounds__(512, 2)
void mfma_gemm_logits(const ushort* __restrict__ A, int lda,
                      const ushort* __restrict__ Bt, int ldb,
                      float* __restrict__ Cf, int ldc,
                      const float* __restrict__ bias,
                      int K,
                      float* __restrict__ smax, float* __restrict__ ssum, int nblks)
{
    __shared__ ushort As[32 * 512];     // 512 rows x 32 k (32 KB)
    __shared__ ushort Bs[8 * 512];      // 128 rows x 32 k (8 KB)
    __shared__ float sstat[2][512][2];  // 8 KB

    const int bxx = blockIdx.x, byy = blockIdx.y;
    const int m0 = byy << 9, n0 = bxx << 7;
    const int tid = threadIdx.x, w = tid >> 6, lane = tid & 63;
    const int wm = w >> 1, wn = w & 1;   // 4 x 2 wave grid
    const int l15 = lane & 15, lk = lane >> 4;

    floatx4 acc[8][4] = {};

    for (int k0 = 0; k0 < K; k0 += 32) {
        // A: 32 chunks of 16 rows x 32 k; wave w stages cg = 4w..4w+3
        #pragma unroll
        for (int i = 0; i < 4; ++i) {
            int cg = 4 * w + i;
            gload16(A + (size_t)(m0 + cg * 16 + l15) * lda + k0 + lk * 8,
                    &As[cg * 512]);
        }
        // B: 8 chunks; wave w stages chunk w
        gload16(Bt + (size_t)(n0 + w * 16 + l15) * ldb + k0 + lk * 8,
                &Bs[w * 512]);
        __syncthreads();
        bf16x8 bfr[4];
        #pragma unroll
        for (int ni = 0; ni < 4; ++ni)
            bfr[ni] = *(const bf16x8*)&Bs[((wn * 4 + ni) * 64 + lane) * 8];
        #pragma unroll
        for (int mi = 0; mi < 8; ++mi) {
            bf16x8 af = *(const bf16x8*)&As[((wm * 8 + mi) * 64 + lane) * 8];
            #pragma unroll
            for (int ni = 0; ni < 4; ++ni)
                acc[mi][ni] = __builtin_amdgcn_mfma_f32_16x16x32_bf16(
                    af, bfr[ni], acc[mi][ni], 0, 0, 0);
        }
        __syncthreads();
    }

    // bias in registers
    #pragma unroll
    for (int ni = 0; ni < 4; ++ni) {
        float bv = bias[n0 + wn * 64 + ni * 16 + l15];
        #pragma unroll
        for (int mi = 0; mi < 8; ++mi)
            #pragma unroll
            for (int r = 0; r < 4; ++r) acc[mi][ni][r] += bv;
    }

    // direct stores
    #pragma unroll
    for (int mi = 0; mi < 8; ++mi) {
        #pragma unroll
        for (int r = 0; r < 4; ++r) {
            int grow = m0 + wm * 128 + mi * 16 + lk * 4 + r;
            #pragma unroll
            for (int ni = 0; ni < 4; ++ni)
                Cf[(size_t)grow * ldc + n0 + wn * 64 + ni * 16 + l15] = acc[mi][ni][r];
        }
    }

    // fused softmax partials (per-row over this 128-col block)
    #pragma unroll
    for (int mi = 0; mi < 8; ++mi) {
        #pragma unroll
        for (int r = 0; r < 4; ++r) {
            float m4 = fmaxf(fmaxf(acc[mi][0][r], acc[mi][1][r]),
                             fmaxf(acc[mi][2][r], acc[mi][3][r]));
            m4 = fmaxf(m4, __shfl_xor(m4, 1));
            m4 = fmaxf(m4, __shfl_xor(m4, 2));
            m4 = fmaxf(m4, __shfl_xor(m4, 4));
            m4 = fmaxf(m4, __shfl_xor(m4, 8));
            float s4 = 0.f;
            #pragma unroll
            for (int ni = 0; ni < 4; ++ni) s4 += __expf(acc[mi][ni][r] - m4);
            s4 += __shfl_xor(s4, 1);
            s4 += __shfl_xor(s4, 2);
            s4 += __shfl_xor(s4, 4);
            s4 += __shfl_xor(s4, 8);
            if (l15 == 0) {
                int R = wm * 128 + mi * 16 + lk * 4 + r;
                sstat[0][R][wn] = m4;
                sstat[1][R][wn] = s4;
            }
        }
    }
    __syncthreads();
    {
        float ma = sstat[0][tid][0], mb = sstat[0][tid][1];
        float M = fmaxf(ma, mb);
        float S = sstat[1][tid][0] * __expf(ma - M)
                + sstat[1][tid][1] * __expf(mb - M);
        smax[(size_t)(m0 + tid) * nblks + bxx] = M;
        ssum[(size_t)(m0 + tid) * nblks + bxx] = S;
    }
}

// ---------------- layer GEMM 128x128: counted-vmcnt double-buffer (T3/T4)
__global__ __launch_bounds__(256, 2)
void mfma_gemm_db(const ushort* __restrict__ A, int lda,
                  const ushort* __restrict__ Bt, int ldb,
                  float* __restrict__ Cf, ushort* __restrict__ Cbf, int ldc,
                  const float* __restrict__ bias,
                  const float* __restrict__ resid, int ldres,
                  int K, int relu)
{
    __shared__ ushort st[2][2][8192];   // [buf][A|B] = 64 KB

    const int m0 = blockIdx.y << 7, n0 = blockIdx.x << 7;
    const int tid = threadIdx.x, w = tid >> 6, lane = tid & 63;
    const int wm = w >> 1, wn = w & 1;
    const int l15 = lane & 15, lk = lane >> 4;
    const int nt = K >> 6;

    auto STAGE = [&](int t, int p) {
        const int k0 = t << 6;
        #pragma unroll
        for (int i = 0; i < 4; ++i) {
            int c = 4 * w + i;
            int cg = c >> 3, cmi = (c >> 1) & 3, ckh = c & 1;
            gload16(A + (size_t)(m0 + cg * 64 + cmi * 16 + l15) * lda
                      + k0 + lk * 8 + ckh * 32, &st[p][0][c * 512]);
            gload16(Bt + (size_t)(n0 + cg * 64 + cmi * 16 + l15) * ldb
                       + k0 + lk * 8 + ckh * 32, &st[p][1][c * 512]);
        }
    };

    floatx4 acc[4][4] = {};
    STAGE(0, 0);

    for (int t = 0; t < nt; ++t) {
        const int p = t & 1;
        if (t + 1 < nt) {
            STAGE(t + 1, p ^ 1);
            asm volatile("s_waitcnt vmcnt(8)" ::: "memory");
        } else {
            asm volatile("s_waitcnt vmcnt(0)" ::: "memory");
        }
        __builtin_amdgcn_s_barrier();
        __builtin_amdgcn_sched_barrier(0);
        #pragma unroll
        for (int kh = 0; kh < 2; ++kh) {
            bf16x8 af[4], bfr[4];
            #pragma unroll
            for (int mi = 0; mi < 4; ++mi)
                af[mi] = *(const bf16x8*)&st[p][0][((wm * 8 + mi * 2 + kh) * 64 + lane) * 8];
            #pragma unroll
            for (int ni = 0; ni < 4; ++ni)
                bfr[ni] = *(const bf16x8*)&st[p][1][((wn * 8 + ni * 2 + kh) * 64 + lane) * 8];
            #pragma unroll
            for (int mi = 0; mi < 4; ++mi)
                #pragma unroll
                for (int ni = 0; ni < 4; ++ni)
                    acc[mi][ni] = __builtin_amdgcn_mfma_f32_16x16x32_bf16(
                        af[mi], bfr[ni], acc[mi][ni], 0, 0, 0);
        }
        __builtin_amdgcn_sched_barrier(0);
        __builtin_amdgcn_s_barrier();
    }

    #pragma unroll
    for (int mi = 0; mi < 4; ++mi)
        #pragma unroll
        for (int ni = 0; ni < 4; ++ni)
            #pragma unroll
            for (int r = 0; r < 4; ++r) {
                float v = acc[mi][ni][r];
                if (bias) v += bias[n0 + wn * 64 + ni * 16 + l15];
                if (relu) v = fmaxf(v, 0.0f);
                acc[mi][ni][r] = v;
            }

    #pragma unroll
    for (int mi = 0; mi < 4; ++mi) {
        #pragma unroll
        for (int r = 0; r < 4; ++r) {
            int grow = m0 + wm * 64 + mi * 16 + lk * 4 + r;
            #pragma unroll
            for (int ni = 0; ni < 4; ++ni) {
                int gcol = n0 + wn * 64 + ni * 16 + l15;
                float v = acc[mi][ni][r];
                if (resid) v += resid[(size_t)grow * ldres + gcol];
                if (Cbf) Cbf[(size_t)grow * ldc + gcol] = f2bf(v);
                else     Cf [(size_t)grow * ldc + gcol] = v;
            }
        }
    }
}

// ---------------- layer GEMM 64x128 (N=512/1536 outputs: >=256-block grids)
__global__ __launch_bounds__(256, 3)
void mfma_gemm_db64(const ushort* __restrict__ A, int lda,
                    const ushort* __restrict__ Bt, int ldb,
                    float* __restrict__ Cf, ushort* __restrict__ Cbf, int ldc,
                    const float* __restrict__ bias,
                    const float* __restrict__ resid, int ldres,
                    int K, int relu)
{
    __shared__ ushort stA[2][8 * 512];
    __shared__ ushort stB[2][16 * 512];

    const int m0 = blockIdx.y << 6, n0 = blockIdx.x << 7;
    const int tid = threadIdx.x, w = tid >> 6, lane = tid & 63;
    const int l15 = lane & 15, lk = lane >> 4;
    const int nt = K >> 6;

    auto STAGE = [&](int t, int p) {
        const int k0 = t << 6;
        #pragma unroll
        for (int i = 0; i < 2; ++i) {
            int c = 2 * w + i;
            int cmi = c >> 1, ckh = c & 1;
            gload16(A + (size_t)(m0 + cmi * 16 + l15) * lda
                      + k0 + lk * 8 + ckh * 32, &stA[p][c * 512]);
        }
        #pragma unroll
        for (int i = 0; i < 4; ++i) {
            int c = 4 * w + i;
            int cnj = c >> 1, ckh = c & 1;
            gload16(Bt + (size_t)(n0 + cnj * 16 + l15) * ldb
                       + k0 + lk * 8 + ckh * 32, &stB[p][c * 512]);
        }
    };

    floatx4 acc[4][2] = {};
    STAGE(0, 0);

    for (int t = 0; t < nt; ++t) {
        const int p = t & 1;
        if (t + 1 < nt) {
            STAGE(t + 1, p ^ 1);
            asm volatile("s_waitcnt vmcnt(6)" ::: "memory");
        } else {
            asm volatile("s_waitcnt vmcnt(0)" ::: "memory");
        }
        __builtin_amdgcn_s_barrier();
        __builtin_amdgcn_sched_barrier(0);
        #pragma unroll
        for (int kh = 0; kh < 2; ++kh) {
            bf16x8 af[4], bfr[2];
            #pragma unroll
            for (int mi = 0; mi < 4; ++mi)
                af[mi] = *(const bf16x8*)&stA[p][((mi * 2 + kh) * 64 + lane) * 8];
            #pragma unroll
            for (int ni = 0; ni < 2; ++ni)
                bfr[ni] = *(const bf16x8*)&stB[p][(((w * 2 + ni) * 2 + kh) * 64 + lane) * 8];
            #pragma unroll
            for (int mi = 0; mi < 4; ++mi)
                #pragma unroll
                for (int ni = 0; ni < 2; ++ni)
                    acc[mi][ni] = __builtin_amdgcn_mfma_f32_16x16x32_bf16(
                        af[mi], bfr[ni], acc[mi][ni], 0, 0, 0);
        }
        __builtin_amdgcn_sched_barrier(0);
        __builtin_amdgcn_s_barrier();
    }

    #pragma unroll
    for (int mi = 0; mi < 4; ++mi)
        #pragma unroll
        for (int ni = 0; ni < 2; ++ni)
            #pragma unroll
            for (int r = 0; r < 4; ++r) {
                float v = acc[mi][ni][r];
                if (bias) v += bias[n0 + w * 32 + ni * 16 + l15];
                if (relu) v = fmaxf(v, 0.0f);
                acc[mi][ni][r] = v;
            }

    #pragma unroll
    for (int mi = 0; mi < 4; ++mi) {
        #pragma unroll
        for (int r = 0; r < 4; ++r) {
            int grow = m0 + mi * 16 + lk * 4 + r;
            #pragma unroll
            for (int ni = 0; ni < 2; ++ni) {
                int gcol = n0 + w * 32 + ni * 16 + l15;
                float v = acc[mi][ni][r];
                if (resid) v += resid[(size_t)grow * ldres + gcol];
                if (Cbf) Cbf[(size_t)grow * ldc + gcol] = f2bf(v);
                else     Cf [(size_t)grow * ldc + gcol] = v;
            }
        }
    }
}

// ---------------- MFMA flash attention (V via gload_lds, K reg-prefetch)
__global__ __launch_bounds__(256)
void attn_mfma_kernel(const ushort* __restrict__ qkv, const ushort* __restrict__ vt,
                      ushort* __restrict__ out)
{
    __shared__ ushort Vl[64 * 64];   // [d][key] linear, swizzled content (8 KB)
    __shared__ ushort Pl[64][72];    // P[q_local][key]

    const int z = blockIdx.y, b = z >> 3, h = z & 7;
    const int q0 = blockIdx.x << 6;
    const int tid = threadIdx.x;
    const int w = tid >> 6, lane = tid & 63;
    const int l15 = lane & 15, g = lane >> 4;
    const float scale = 0.04419417382415922f;  // 1/sqrt(512)
    const ushort* vbase = vt + (size_t)z * 64 * TT;

    bf16x8 qf0, qf1;
    {
        const ushort* qp = qkv + ((size_t)(b * TT + q0 + 16 * w + l15)) * 1536
                               + h * HSS + g * 8;
        qf0 = *(const bf16x8*)qp;
        qf1 = *(const bf16x8*)(qp + 32);
    }

    bf16x8 kc[8], kn[8];
    {
        #pragma unroll
        for (int kb = 0; kb < 4; ++kb) {
            const ushort* kp = qkv + ((size_t)(b * TT + kb * 16 + l15)) * 1536
                                   + 512 + h * HSS + g * 8;
            kc[kb * 2]     = *(const bf16x8*)kp;
            kc[kb * 2 + 1] = *(const bf16x8*)(kp + 32);
        }
    }

    floatx4 acc_o[4] = {};
    float lreg[4] = {};

    for (int s0 = 0; s0 <= q0; s0 += 64) {
        __syncthreads();
        #pragma unroll
        for (int i = 0; i < 2; ++i) {
            const int cbase = (w * 2 + i) * 64;
            const int c = cbase + lane;
            const int row = c >> 3;
            const int kg = (c & 7) ^ (row & 7);
            gload16(vbase + (size_t)row * TT + s0 + kg * 8, &Vl[cbase * 8]);
        }

        floatx4 s4[4] = {};
        #pragma unroll
        for (int kb = 0; kb < 4; ++kb) {
            s4[kb] = __builtin_amdgcn_mfma_f32_16x16x32_bf16(qf0, kc[kb*2],   s4[kb], 0, 0, 0);
            s4[kb] = __builtin_amdgcn_mfma_f32_16x16x32_bf16(qf1, kc[kb*2+1], s4[kb], 0, 0, 0);
        }

        const bool more = (s0 + 64 <= q0);
        if (more) {
            #pragma unroll
            for (int kb = 0; kb < 4; ++kb) {
                const ushort* kp = qkv + ((size_t)(b * TT + s0 + 64 + kb * 16 + l15)) * 1536
                                       + 512 + h * HSS + g * 8;
                kn[kb * 2]     = *(const bf16x8*)kp;
                kn[kb * 2 + 1] = *(const bf16x8*)(kp + 32);
            }
        }

        const bool diag = (s0 == q0);
        #pragma unroll
        for (int r = 0; r < 4; ++r) {
            const int qrow = q0 + 16 * w + g * 4 + r;
            #pragma unroll
            for (int kb = 0; kb < 4; ++kb) {
                float xs = s4[kb][r] * scale;
                if (diag && (s0 + kb * 16 + l15) > qrow) xs = -1e30f;
                float p = __expf(xs);
                lreg[r] += p;
                Pl[16 * w + g * 4 + r][kb * 16 + l15] = f2bf(p);
            }
        }
        __syncthreads();

        bf16x8 pa0 = *(const bf16x8*)&Pl[16 * w + l15][g * 8];
        bf16x8 pa1 = *(const bf16x8*)&Pl[16 * w + l15][g * 8 + 32];
        #pragma unroll
        for (int db = 0; db < 4; ++db) {
            const int row = db * 16 + l15;
            const bf16x8 vb0 = *(const bf16x8*)&Vl[row * 64 + ((g       ^ (row & 7)) * 8)];
            const bf16x8 vb1 = *(const bf16x8*)&Vl[row * 64 + (((g + 4) ^ (row & 7)) * 8)];
            acc_o[db] = __builtin_amdgcn_mfma_f32_16x16x32_bf16(pa0, vb0, acc_o[db], 0, 0, 0);
            acc_o[db] = __builtin_amdgcn_mfma_f32_16x16x32_bf16(pa1, vb1, acc_o[db], 0, 0, 0);
        }

        if (more) {
            #pragma unroll
            for (int i = 0; i < 8; ++i) kc[i] = kn[i];
        }
    }

    #pragma unroll
    for (int r = 0; r < 4; ++r) {
        float l = lreg[r];
        l += __shfl_xor(l, 1);
        l += __shfl_xor(l, 2);
        l += __shfl_xor(l, 4);
        l += __shfl_xor(l, 8);
        float inv = 1.0f / l;
        ushort* op = out + ((size_t)(b * TT + q0 + 16 * w + g * 4 + r)) * DD + h * HSS;
        #pragma unroll
        for (int db = 0; db < 4; ++db)
            op[db * 16 + l15] = f2bf(acc_o[db][r] * inv);
    }
}

// ---------------- combine per-block softmax partials into per-row loss
__global__ __launch_bounds__(256)
void rowloss_finalize(const float* __restrict__ logits, const int* __restrict__ targets,
                      const float* __restrict__ smax, const float* __restrict__ ssum,
                      float* __restrict__ rowloss)
{
    const int wv = threadIdx.x >> 6, lane = threadIdx.x & 63;
    const int row = blockIdx.x * 4 + wv;
    const float* mrow = smax + (size_t)row * NBLK_V;
    const float* srow = ssum + (size_t)row * NBLK_V;
    float M = -1e30f;
    for (int i = lane; i < NBLK_V; i += 64) M = fmaxf(M, mrow[i]);
    #pragma unroll
    for (int off = 32; off; off >>= 1) M = fmaxf(M, __shfl_xor(M, off));
    float S = 0.f;
    for (int i = lane; i < NBLK_V; i += 64) S += srow[i] * __expf(mrow[i] - M);
    #pragma unroll
    for (int off = 32; off; off >>= 1) S += __shfl_xor(S, off);
    if (lane == 0)
        rowloss[row] = -(logits[(size_t)row * VV + targets[row]] - M - logf(S));
}

__global__ __launch_bounds__(256)
void loss_finalize(const float* __restrict__ rowloss, float* __restrict__ out)
{
    __shared__ float red[256];
    float s = 0.f;
    for (int i = threadIdx.x; i < BB * TT; i += 256) s += rowloss[i];
    red[threadIdx.x] = s; __syncthreads();
    for (int s2 = 128; s2; s2 >>= 1) {
        if (threadIdx.x < s2) red[threadIdx.x] += red[threadIdx.x + s2];
        __syncthreads();
    }
    if (threadIdx.x == 0) out[0] = red[0] * (1.0f / (BB * TT));
}

extern "C" void kernel_launch(void* const* d_in, const int* in_sizes, int n_in,
                              void* d_out, int out_size, void* d_ws, size_t ws_size,
                              hipStream_t stream) {
    const int*   idx     = (const int*)  d_in[0];
    const int*   targets = (const int*)  d_in[1];
    const float* tok_emb = (const float*)d_in[2];
    const float* pos_emb = (const float*)d_in[3];
    const float* ln1_g   = (const float*)d_in[4];
    const float* ln1_b   = (const float*)d_in[5];
    const float* Wq      = (const float*)d_in[6];
    const float* Wk      = (const float*)d_in[7];
    const float* Wv      = (const float*)d_in[8];
    const float* Wo      = (const float*)d_in[9];
    const float* bo      = (const float*)d_in[10];
    const float* ln2_g   = (const float*)d_in[11];
    const float* ln2_b   = (const float*)d_in[12];
    const float* W1      = (const float*)d_in[13];
    const float* b1      = (const float*)d_in[14];
    const float* W2      = (const float*)d_in[15];
    const float* b2      = (const float*)d_in[16];
    const float* lnf_g   = (const float*)d_in[17];
    const float* lnf_b   = (const float*)d_in[18];
    const float* Wout    = (const float*)d_in[19];
    const float* bout    = (const float*)d_in[20];

    float* outf   = (float*)d_out;
    float* logits = outf + 1;                   // [B*T, V] fp32

    const size_t ROW = (size_t)BB * TT;         // 4096

    // ---- d_ws: x (fp32) | h_bf | Wout^T (bf16) | rowloss
    float*  x     = (float*)d_ws;
    ushort* h_bf  = (ushort*)(x + ROW * DD);
    ushort* Woutt = h_bf + ROW * DD;
    float*  rowloss = (float*)(Woutt + (size_t)VV * DD);
    float* smax = x;                            // ROW * NBLK_V (x dead by then)
    float* ssum = x + ROW * NBLK_V;

    // ---- scratch inside the (dead-until-final) logits region of d_out
    ushort* sc     = (ushort*)(outf + 8);
    ushort* qkv_bf = sc;                        // ROW*1536
    ushort* ff_bf  = qkv_bf + ROW * 1536;       // ROW*2048
    ushort* Wqkvt  = ff_bf + ROW * FF_;         // L*1536*512
    ushort* Wot    = Wqkvt + (size_t)LL * 1536 * DD;
    ushort* W1t    = Wot   + (size_t)LL * DD * DD;
    ushort* W2t    = W1t   + (size_t)LL * FF_ * DD;
    ushort* vt_g   = W2t   + (size_t)LL * DD * FF_;   // BB*HH*64*TT (4.2 MB)

    qkv_transpose<<<dim3(8, 96), 256, 0, stream>>>(Wq, Wk, Wv, Wqkvt);
    transpose_cvt<<<dim3(8, 8, LL),  256, 0, stream>>>(Wo,   Wot,   DD,  DD,  (long)DD*DD,   (long)DD*DD);
    transpose_cvt<<<dim3(32, 8, LL), 256, 0, stream>>>(W1,   W1t,   FF_, DD,  (long)DD*FF_,  (long)DD*FF_);
    transpose_cvt<<<dim3(8, 32, LL), 256, 0, stream>>>(W2,   W2t,   DD,  FF_, (long)FF_*DD,  (long)FF_*DD);
    transpose_cvt<<<dim3(500, 8, 1), 256, 0, stream>>>(Wout, Woutt, VV,  DD,  0, 0);

    embed_kernel<<<ROW, 64, 0, stream>>>(idx, tok_emb, pos_emb, x);

    for (int l = 0; l < LL; ++l) {
        ln_kernel<<<ROW / 4, 256, 0, stream>>>(x, ln1_g + l * DD, ln1_b + l * DD, h_bf);

        // QKV: 64x128 tiles -> 768-block grid (full CU coverage; was 384)
        mfma_gemm_db64<<<dim3(1536 / 128, ROW / 64), 256, 0, stream>>>(
            h_bf, DD, Wqkvt + (size_t)l * 1536 * DD, DD,
            nullptr, qkv_bf, 1536, nullptr, nullptr, 0, DD, 0);

        v_transpose<<<dim3(TT / 64, BB * HH), 256, 0, stream>>>(qkv_bf, vt_g);

        attn_mfma_kernel<<<dim3(TT / 64, BB * HH), 256, 0, stream>>>(qkv_bf, vt_g, h_bf);

        mfma_gemm_db64<<<dim3(DD / 128, ROW / 64), 256, 0, stream>>>(
            h_bf, DD, Wot + (size_t)l * DD * DD, DD,
            x, nullptr, DD, bo + l * DD, x, DD, DD, 0);

        ln_kernel<<<ROW / 4, 256, 0, stream>>>(x, ln2_g + l * DD, ln2_b + l * DD, h_bf);

        mfma_gemm_db<<<dim3(FF_ / 128, ROW / 128), 256, 0, stream>>>(
            h_bf, DD, W1t + (size_t)l * FF_ * DD, DD,
            nullptr, ff_bf, FF_, b1 + l * FF_, nullptr, 0, DD, 1);

        mfma_gemm_db64<<<dim3(DD / 128, ROW / 64), 256, 0, stream>>>(
            ff_bf, FF_, W2t + (size_t)l * DD * FF_, FF_,
            x, nullptr, DD, b2 + l * DD, x, DD, FF_, 0);
    }

    ln_kernel<<<ROW / 4, 256, 0, stream>>>(x, lnf_g, lnf_b, h_bf);

    // logits GEMM: BM=512 halves B-panel sweeps to 8 (FETCH ~halved)
    mfma_gemm_logits<<<dim3(VV / 128, ROW / 512), 512, 0, stream>>>(
        h_bf, DD, Woutt, DD,
        logits, VV, bout, DD,
        smax, ssum, NBLK_V);

    rowloss_finalize<<<ROW / 4, 256, 0, stream>>>(logits, targets, smax, ssum, rowloss);
    loss_finalize<<<1, 256, 0, stream>>>(rowloss, outf);
}

// Round 21
// 1228.172 us; speedup vs baseline: 1.1030x; 1.1030x over previous
//
#include <hip/hip_runtime.h>
#include <hip/hip_bf16.h>
#include <math.h>

#define TT 2048
#define BB 2
#define VV 32000
#define DD 512
#define HH 8
#define HSS 64
#define LL 4
#define FF_ 2048
#define NBLK_V (VV / 128)   // 250

using bf16x8 = __attribute__((ext_vector_type(8))) short;
using floatx4 = __attribute__((ext_vector_type(4))) float;

__device__ __forceinline__ ushort f2bf(float f) {
    __hip_bfloat16 b = __float2bfloat16(f);
    return *reinterpret_cast<ushort*>(&b);
}
__device__ __forceinline__ float bf2f(ushort u) {
    union { unsigned int i; float f; } x; x.i = ((unsigned int)u) << 16; return x.f;
}
__device__ __forceinline__ void gload16(const void* g, void* l) {
    __builtin_amdgcn_global_load_lds(
        (const __attribute__((address_space(1))) void*)g,
        (__attribute__((address_space(3))) void*)l, 16, 0, 0);
}

// ---------------- embedding
__global__ __launch_bounds__(64)
void embed_kernel(const int* __restrict__ idx, const float* __restrict__ tok,
                  const float* __restrict__ pos, float* __restrict__ x)
{
    int row = blockIdx.x;
    int t = row & (TT - 1);
    int tokid = idx[row];
    int lane = threadIdx.x;
    const float4* tp = (const float4*)(tok + (size_t)tokid * DD);
    const float4* pp = (const float4*)(pos + (size_t)t * DD);
    float4* xp = (float4*)(x + (size_t)row * DD);
    int i0 = lane * 2;
    float4 a = tp[i0],   b4 = pp[i0];
    float4 c = tp[i0+1], d4 = pp[i0+1];
    xp[i0]   = make_float4(a.x + b4.x, a.y + b4.y, a.z + b4.z, a.w + b4.w);
    xp[i0+1] = make_float4(c.x + d4.x, c.y + d4.y, c.z + d4.z, c.w + d4.w);
}

// ---------------- layernorm -> bf16
__global__ __launch_bounds__(256)
void ln_kernel(const float* __restrict__ x, const float* __restrict__ g,
               const float* __restrict__ b, ushort* __restrict__ out)
{
    int wave = threadIdx.x >> 6;
    int lane = threadIdx.x & 63;
    int row  = blockIdx.x * 4 + wave;
    const float* xr = x + (size_t)row * DD;
    float4 v0 = *(const float4*)(xr + lane * 8);
    float4 v1 = *(const float4*)(xr + lane * 8 + 4);
    float s = v0.x + v0.y + v0.z + v0.w + v1.x + v1.y + v1.z + v1.w;
    float q = v0.x*v0.x + v0.y*v0.y + v0.z*v0.z + v0.w*v0.w
            + v1.x*v1.x + v1.y*v1.y + v1.z*v1.z + v1.w*v1.w;
    #pragma unroll
    for (int off = 32; off; off >>= 1) {
        s += __shfl_xor(s, off);
        q += __shfl_xor(q, off);
    }
    float mu  = s * (1.0f / DD);
    float var = q * (1.0f / DD) - mu * mu;
    float rs  = rsqrtf(var + 1e-5f);
    float4 g0 = *(const float4*)(g + lane * 8);
    float4 g1 = *(const float4*)(g + lane * 8 + 4);
    float4 b0 = *(const float4*)(b + lane * 8);
    float4 b1 = *(const float4*)(b + lane * 8 + 4);
    union { ushort u[8]; uint4 v; } pk;
    pk.u[0] = f2bf((v0.x - mu) * rs * g0.x + b0.x);
    pk.u[1] = f2bf((v0.y - mu) * rs * g0.y + b0.y);
    pk.u[2] = f2bf((v0.z - mu) * rs * g0.z + b0.z);
    pk.u[3] = f2bf((v0.w - mu) * rs * g0.w + b0.w);
    pk.u[4] = f2bf((v1.x - mu) * rs * g1.x + b1.x);
    pk.u[5] = f2bf((v1.y - mu) * rs * g1.y + b1.y);
    pk.u[6] = f2bf((v1.z - mu) * rs * g1.z + b1.z);
    pk.u[7] = f2bf((v1.w - mu) * rs * g1.w + b1.w);
    *(uint4*)(out + (size_t)row * DD + lane * 8) = pk.v;
}

// ---------------- transpose+convert: in [K][N] f32 -> out [N][K] bf16
__global__ __launch_bounds__(256)
void transpose_cvt(const float* __restrict__ in, ushort* __restrict__ out,
                   int N, int K, long inStrideZ, long outStrideZ)
{
    __shared__ float t[64][65];
    in  += (size_t)blockIdx.z * inStrideZ;
    out += (size_t)blockIdx.z * outStrideZ;
    const int n0 = blockIdx.x * 64, k0 = blockIdx.y * 64;
    const int r = threadIdx.x >> 2;
    const int c = (threadIdx.x & 3) * 16;
    #pragma unroll
    for (int j = 0; j < 16; j += 4) {
        float4 v = *(const float4*)&in[(size_t)(k0 + r) * N + n0 + c + j];
        t[r][c + j + 0] = v.x; t[r][c + j + 1] = v.y;
        t[r][c + j + 2] = v.z; t[r][c + j + 3] = v.w;
    }
    __syncthreads();
    union { ushort u[8]; uint4 v; } pk;
    ushort* orow = out + (size_t)(n0 + r) * K + k0 + c;
    #pragma unroll
    for (int half = 0; half < 2; ++half) {
        #pragma unroll
        for (int j = 0; j < 8; ++j) pk.u[j] = f2bf(t[c + half * 8 + j][r]);
        *(uint4*)(orow + half * 8) = pk.v;
    }
}

// ---------------- QKV weights -> fused [L][1536][512] bf16
__global__ __launch_bounds__(256)
void qkv_transpose(const float* __restrict__ Wq, const float* __restrict__ Wk,
                   const float* __restrict__ Wv, ushort* __restrict__ out)
{
    __shared__ float t[64][65];
    const int z = blockIdx.y;
    const int sel = z >> 5, l = (z >> 3) & 3, h = z & 7;
    const float* in = (sel == 0 ? Wq : sel == 1 ? Wk : Wv)
                      + (size_t)l * (HH * DD * HSS) + (size_t)h * (DD * HSS);
    ushort* ob = out + (size_t)l * (3 * DD * DD) + (size_t)sel * (DD * DD)
                     + (size_t)h * (HSS * DD);
    const int d0 = blockIdx.x * 64;
    const int r = threadIdx.x >> 2;
    const int c = (threadIdx.x & 3) * 16;
    #pragma unroll
    for (int j = 0; j < 16; j += 4) {
        float4 v = *(const float4*)&in[(size_t)(d0 + r) * HSS + c + j];
        t[r][c + j + 0] = v.x; t[r][c + j + 1] = v.y;
        t[r][c + j + 2] = v.z; t[r][c + j + 3] = v.w;
    }
    __syncthreads();
    union { ushort u[8]; uint4 v; } pk;
    ushort* orow = ob + (size_t)r * DD + d0 + c;
    #pragma unroll
    for (int half = 0; half < 2; ++half) {
        #pragma unroll
        for (int j = 0; j < 8; ++j) pk.u[j] = f2bf(t[c + half * 8 + j][r]);
        *(uint4*)(orow + half * 8) = pk.v;
    }
}

// ---------------- V -> vt[bh][d][T] bf16 (per-layer, 4.2 MB)
__global__ __launch_bounds__(256)
void v_transpose(const ushort* __restrict__ qkv, ushort* __restrict__ vt)
{
    __shared__ ushort t[64][72];
    const int z = blockIdx.y;            // b*H + h
    const int t0 = blockIdx.x * 64;
    const int b = z >> 3, h = z & 7;
    const int tr = threadIdx.x >> 2;
    const int dc = (threadIdx.x & 3) * 16;
    const ushort* src = qkv + ((size_t)(b * TT + t0 + tr)) * 1536 + 1024 + h * HSS + dc;
    *(uint4*)&t[tr][dc]     = *(const uint4*)src;
    *(uint4*)&t[tr][dc + 8] = *(const uint4*)(src + 8);
    __syncthreads();
    const int dr = threadIdx.x >> 2;
    const int tc = (threadIdx.x & 3) * 16;
    ushort* dst = vt + ((size_t)z * 64 + dr) * TT + t0 + tc;
    union { ushort u[8]; uint4 v; } p0, p1;
    #pragma unroll
    for (int j = 0; j < 8; ++j) { p0.u[j] = t[tc + j][dr]; p1.u[j] = t[tc + 8 + j][dr]; }
    *(uint4*)dst       = p0.v;
    *(uint4*)(dst + 8) = p1.v;
}

// ---------------- logits GEMM: BM=256 x BN=128, BK=64, single-buffer
// R16-proven Pareto point: 284 MB fetch, 42% occupancy, ~316 us.
__global__ __launch_bounds__(512, 2)
void mfma_gemm_logits(const ushort* __restrict__ A, int lda,
                      const ushort* __restrict__ Bt, int ldb,
                      float* __restrict__ Cf, int ldc,
                      const float* __restrict__ bias,
                      int K,
                      float* __restrict__ smax, float* __restrict__ ssum, int nblks)
{
    __shared__ ushort As[32 * 512];
    __shared__ ushort Bs[16 * 512];
    __shared__ float sstat[2][256][2];

    const int bxx = blockIdx.x, byy = blockIdx.y;
    const int m0 = byy << 8, n0 = bxx << 7;
    const int tid = threadIdx.x, w = tid >> 6, lane = tid & 63;
    const int wm = w >> 1, wn = w & 1;
    const int l15 = lane & 15, lk = lane >> 4;

    floatx4 acc[4][4] = {};

    for (int k0 = 0; k0 < K; k0 += 64) {
        #pragma unroll
        for (int i = 0; i < 4; ++i) {
            int c = 4 * w + i;
            int cg = c >> 1, ckh = c & 1;
            gload16(A + (size_t)(m0 + cg * 16 + l15) * lda + k0 + lk * 8 + ckh * 32,
                    &As[c * 512]);
        }
        #pragma unroll
        for (int i = 0; i < 2; ++i) {
            int c = 2 * w + i;
            int cg = c >> 1, ckh = c & 1;
            gload16(Bt + (size_t)(n0 + cg * 16 + l15) * ldb + k0 + lk * 8 + ckh * 32,
                    &Bs[c * 512]);
        }
        __syncthreads();
        #pragma unroll
        for (int kh = 0; kh < 2; ++kh) {
            bf16x8 af[4], bfr[4];
            #pragma unroll
            for (int mi = 0; mi < 4; ++mi)
                af[mi] = *(const bf16x8*)&As[(((wm * 4 + mi) * 2 + kh) * 64 + lane) * 8];
            #pragma unroll
            for (int ni = 0; ni < 4; ++ni)
                bfr[ni] = *(const bf16x8*)&Bs[(((wn * 4 + ni) * 2 + kh) * 64 + lane) * 8];
            #pragma unroll
            for (int mi = 0; mi < 4; ++mi)
                #pragma unroll
                for (int ni = 0; ni < 4; ++ni)
                    acc[mi][ni] = __builtin_amdgcn_mfma_f32_16x16x32_bf16(
                        af[mi], bfr[ni], acc[mi][ni], 0, 0, 0);
        }
        __syncthreads();
    }

    #pragma unroll
    for (int mi = 0; mi < 4; ++mi)
        #pragma unroll
        for (int ni = 0; ni < 4; ++ni) {
            float bv = bias[n0 + wn * 64 + ni * 16 + l15];
            #pragma unroll
            for (int r = 0; r < 4; ++r) acc[mi][ni][r] += bv;
        }

    #pragma unroll
    for (int mi = 0; mi < 4; ++mi) {
        #pragma unroll
        for (int r = 0; r < 4; ++r) {
            int grow = m0 + wm * 64 + mi * 16 + lk * 4 + r;
            #pragma unroll
            for (int ni = 0; ni < 4; ++ni)
                Cf[(size_t)grow * ldc + n0 + wn * 64 + ni * 16 + l15] = acc[mi][ni][r];
        }
    }

    #pragma unroll
    for (int mi = 0; mi < 4; ++mi) {
        #pragma unroll
        for (int r = 0; r < 4; ++r) {
            float m4 = fmaxf(fmaxf(acc[mi][0][r], acc[mi][1][r]),
                             fmaxf(acc[mi][2][r], acc[mi][3][r]));
            m4 = fmaxf(m4, __shfl_xor(m4, 1));
            m4 = fmaxf(m4, __shfl_xor(m4, 2));
            m4 = fmaxf(m4, __shfl_xor(m4, 4));
            m4 = fmaxf(m4, __shfl_xor(m4, 8));
            float s4 = 0.f;
            #pragma unroll
            for (int ni = 0; ni < 4; ++ni) s4 += __expf(acc[mi][ni][r] - m4);
            s4 += __shfl_xor(s4, 1);
            s4 += __shfl_xor(s4, 2);
            s4 += __shfl_xor(s4, 4);
            s4 += __shfl_xor(s4, 8);
            if (l15 == 0) {
                int R = wm * 64 + mi * 16 + lk * 4 + r;
                sstat[0][R][wn] = m4;
                sstat[1][R][wn] = s4;
            }
        }
    }
    __syncthreads();
    if (tid < 256) {
        float ma = sstat[0][tid][0], mb = sstat[0][tid][1];
        float M = fmaxf(ma, mb);
        float S = sstat[1][tid][0] * __expf(ma - M)
                + sstat[1][tid][1] * __expf(mb - M);
        smax[(size_t)(m0 + tid) * nblks + bxx] = M;
        ssum[(size_t)(m0 + tid) * nblks + bxx] = S;
    }
}

// ---------------- layer GEMM 128x128: counted-vmcnt double-buffer (T3/T4)
__global__ __launch_bounds__(256, 2)
void mfma_gemm_db(const ushort* __restrict__ A, int lda,
                  const ushort* __restrict__ Bt, int ldb,
                  float* __restrict__ Cf, ushort* __restrict__ Cbf, int ldc,
                  const float* __restrict__ bias,
                  const float* __restrict__ resid, int ldres,
                  int K, int relu)
{
    __shared__ ushort st[2][2][8192];   // [buf][A|B] = 64 KB

    const int m0 = blockIdx.y << 7, n0 = blockIdx.x << 7;
    const int tid = threadIdx.x, w = tid >> 6, lane = tid & 63;
    const int wm = w >> 1, wn = w & 1;
    const int l15 = lane & 15, lk = lane >> 4;
    const int nt = K >> 6;

    auto STAGE = [&](int t, int p) {
        const int k0 = t << 6;
        #pragma unroll
        for (int i = 0; i < 4; ++i) {
            int c = 4 * w + i;
            int cg = c >> 3, cmi = (c >> 1) & 3, ckh = c & 1;
            gload16(A + (size_t)(m0 + cg * 64 + cmi * 16 + l15) * lda
                      + k0 + lk * 8 + ckh * 32, &st[p][0][c * 512]);
            gload16(Bt + (size_t)(n0 + cg * 64 + cmi * 16 + l15) * ldb
                       + k0 + lk * 8 + ckh * 32, &st[p][1][c * 512]);
        }
    };

    floatx4 acc[4][4] = {};
    STAGE(0, 0);

    for (int t = 0; t < nt; ++t) {
        const int p = t & 1;
        if (t + 1 < nt) {
            STAGE(t + 1, p ^ 1);
            asm volatile("s_waitcnt vmcnt(8)" ::: "memory");
        } else {
            asm volatile("s_waitcnt vmcnt(0)" ::: "memory");
        }
        __builtin_amdgcn_s_barrier();
        __builtin_amdgcn_sched_barrier(0);
        #pragma unroll
        for (int kh = 0; kh < 2; ++kh) {
            bf16x8 af[4], bfr[4];
            #pragma unroll
            for (int mi = 0; mi < 4; ++mi)
                af[mi] = *(const bf16x8*)&st[p][0][((wm * 8 + mi * 2 + kh) * 64 + lane) * 8];
            #pragma unroll
            for (int ni = 0; ni < 4; ++ni)
                bfr[ni] = *(const bf16x8*)&st[p][1][((wn * 8 + ni * 2 + kh) * 64 + lane) * 8];
            #pragma unroll
            for (int mi = 0; mi < 4; ++mi)
                #pragma unroll
                for (int ni = 0; ni < 4; ++ni)
                    acc[mi][ni] = __builtin_amdgcn_mfma_f32_16x16x32_bf16(
                        af[mi], bfr[ni], acc[mi][ni], 0, 0, 0);
        }
        __builtin_amdgcn_sched_barrier(0);
        __builtin_amdgcn_s_barrier();
    }

    #pragma unroll
    for (int mi = 0; mi < 4; ++mi)
        #pragma unroll
        for (int ni = 0; ni < 4; ++ni)
            #pragma unroll
            for (int r = 0; r < 4; ++r) {
                float v = acc[mi][ni][r];
                if (bias) v += bias[n0 + wn * 64 + ni * 16 + l15];
                if (relu) v = fmaxf(v, 0.0f);
                acc[mi][ni][r] = v;
            }

    #pragma unroll
    for (int mi = 0; mi < 4; ++mi) {
        #pragma unroll
        for (int r = 0; r < 4; ++r) {
            int grow = m0 + wm * 64 + mi * 16 + lk * 4 + r;
            #pragma unroll
            for (int ni = 0; ni < 4; ++ni) {
                int gcol = n0 + wn * 64 + ni * 16 + l15;
                float v = acc[mi][ni][r];
                if (resid) v += resid[(size_t)grow * ldres + gcol];
                if (Cbf) Cbf[(size_t)grow * ldc + gcol] = f2bf(v);
                else     Cf [(size_t)grow * ldc + gcol] = v;
            }
        }
    }
}

// ---------------- layer GEMM 64x128 (for N=512 outputs: 256-block grids)
__global__ __launch_bounds__(256, 3)
void mfma_gemm_db64(const ushort* __restrict__ A, int lda,
                    const ushort* __restrict__ Bt, int ldb,
                    float* __restrict__ Cf, ushort* __restrict__ Cbf, int ldc,
                    const float* __restrict__ bias,
                    const float* __restrict__ resid, int ldres,
                    int K, int relu)
{
    __shared__ ushort stA[2][8 * 512];
    __shared__ ushort stB[2][16 * 512];

    const int m0 = blockIdx.y << 6, n0 = blockIdx.x << 7;
    const int tid = threadIdx.x, w = tid >> 6, lane = tid & 63;
    const int l15 = lane & 15, lk = lane >> 4;
    const int nt = K >> 6;

    auto STAGE = [&](int t, int p) {
        const int k0 = t << 6;
        #pragma unroll
        for (int i = 0; i < 2; ++i) {
            int c = 2 * w + i;
            int cmi = c >> 1, ckh = c & 1;
            gload16(A + (size_t)(m0 + cmi * 16 + l15) * lda
                      + k0 + lk * 8 + ckh * 32, &stA[p][c * 512]);
        }
        #pragma unroll
        for (int i = 0; i < 4; ++i) {
            int c = 4 * w + i;
            int cnj = c >> 1, ckh = c & 1;
            gload16(Bt + (size_t)(n0 + cnj * 16 + l15) * ldb
                       + k0 + lk * 8 + ckh * 32, &stB[p][c * 512]);
        }
    };

    floatx4 acc[4][2] = {};
    STAGE(0, 0);

    for (int t = 0; t < nt; ++t) {
        const int p = t & 1;
        if (t + 1 < nt) {
            STAGE(t + 1, p ^ 1);
            asm volatile("s_waitcnt vmcnt(6)" ::: "memory");
        } else {
            asm volatile("s_waitcnt vmcnt(0)" ::: "memory");
        }
        __builtin_amdgcn_s_barrier();
        __builtin_amdgcn_sched_barrier(0);
        #pragma unroll
        for (int kh = 0; kh < 2; ++kh) {
            bf16x8 af[4], bfr[2];
            #pragma unroll
            for (int mi = 0; mi < 4; ++mi)
                af[mi] = *(const bf16x8*)&stA[p][((mi * 2 + kh) * 64 + lane) * 8];
            #pragma unroll
            for (int ni = 0; ni < 2; ++ni)
                bfr[ni] = *(const bf16x8*)&stB[p][(((w * 2 + ni) * 2 + kh) * 64 + lane) * 8];
            #pragma unroll
            for (int mi = 0; mi < 4; ++mi)
                #pragma unroll
                for (int ni = 0; ni < 2; ++ni)
                    acc[mi][ni] = __builtin_amdgcn_mfma_f32_16x16x32_bf16(
                        af[mi], bfr[ni], acc[mi][ni], 0, 0, 0);
        }
        __builtin_amdgcn_sched_barrier(0);
        __builtin_amdgcn_s_barrier();
    }

    #pragma unroll
    for (int mi = 0; mi < 4; ++mi)
        #pragma unroll
        for (int ni = 0; ni < 2; ++ni)
            #pragma unroll
            for (int r = 0; r < 4; ++r) {
                float v = acc[mi][ni][r];
                if (bias) v += bias[n0 + w * 32 + ni * 16 + l15];
                if (relu) v = fmaxf(v, 0.0f);
                acc[mi][ni][r] = v;
            }

    #pragma unroll
    for (int mi = 0; mi < 4; ++mi) {
        #pragma unroll
        for (int r = 0; r < 4; ++r) {
            int grow = m0 + mi * 16 + lk * 4 + r;
            #pragma unroll
            for (int ni = 0; ni < 2; ++ni) {
                int gcol = n0 + w * 32 + ni * 16 + l15;
                float v = acc[mi][ni][r];
                if (resid) v += resid[(size_t)grow * ldres + gcol];
                if (Cbf) Cbf[(size_t)grow * ldc + gcol] = f2bf(v);
                else     Cf [(size_t)grow * ldc + gcol] = v;
            }
        }
    }
}

// ---------------- MFMA flash attention (V via gload_lds, K reg-prefetch)
__global__ __launch_bounds__(256)
void attn_mfma_kernel(const ushort* __restrict__ qkv, const ushort* __restrict__ vt,
                      ushort* __restrict__ out)
{
    __shared__ ushort Vl[64 * 64];   // [d][key] linear, swizzled content (8 KB)
    __shared__ ushort Pl[64][72];    // P[q_local][key]

    const int z = blockIdx.y, b = z >> 3, h = z & 7;
    const int q0 = blockIdx.x << 6;
    const int tid = threadIdx.x;
    const int w = tid >> 6, lane = tid & 63;
    const int l15 = lane & 15, g = lane >> 4;
    const float scale = 0.04419417382415922f;  // 1/sqrt(512)
    const ushort* vbase = vt + (size_t)z * 64 * TT;

    bf16x8 qf0, qf1;
    {
        const ushort* qp = qkv + ((size_t)(b * TT + q0 + 16 * w + l15)) * 1536
                               + h * HSS + g * 8;
        qf0 = *(const bf16x8*)qp;
        qf1 = *(const bf16x8*)(qp + 32);
    }

    bf16x8 kc[8], kn[8];
    {
        #pragma unroll
        for (int kb = 0; kb < 4; ++kb) {
            const ushort* kp = qkv + ((size_t)(b * TT + kb * 16 + l15)) * 1536
                                   + 512 + h * HSS + g * 8;
            kc[kb * 2]     = *(const bf16x8*)kp;
            kc[kb * 2 + 1] = *(const bf16x8*)(kp + 32);
        }
    }

    floatx4 acc_o[4] = {};
    float lreg[4] = {};

    for (int s0 = 0; s0 <= q0; s0 += 64) {
        __syncthreads();
        #pragma unroll
        for (int i = 0; i < 2; ++i) {
            const int cbase = (w * 2 + i) * 64;
            const int c = cbase + lane;
            const int row = c >> 3;
            const int kg = (c & 7) ^ (row & 7);
            gload16(vbase + (size_t)row * TT + s0 + kg * 8, &Vl[cbase * 8]);
        }

        floatx4 s4[4] = {};
        #pragma unroll
        for (int kb = 0; kb < 4; ++kb) {
            s4[kb] = __builtin_amdgcn_mfma_f32_16x16x32_bf16(qf0, kc[kb*2],   s4[kb], 0, 0, 0);
            s4[kb] = __builtin_amdgcn_mfma_f32_16x16x32_bf16(qf1, kc[kb*2+1], s4[kb], 0, 0, 0);
        }

        const bool more = (s0 + 64 <= q0);
        if (more) {
            #pragma unroll
            for (int kb = 0; kb < 4; ++kb) {
                const ushort* kp = qkv + ((size_t)(b * TT + s0 + 64 + kb * 16 + l15)) * 1536
                                       + 512 + h * HSS + g * 8;
                kn[kb * 2]     = *(const bf16x8*)kp;
                kn[kb * 2 + 1] = *(const bf16x8*)(kp + 32);
            }
        }

        const bool diag = (s0 == q0);
        #pragma unroll
        for (int r = 0; r < 4; ++r) {
            const int qrow = q0 + 16 * w + g * 4 + r;
            #pragma unroll
            for (int kb = 0; kb < 4; ++kb) {
                float xs = s4[kb][r] * scale;
                if (diag && (s0 + kb * 16 + l15) > qrow) xs = -1e30f;
                float p = __expf(xs);
                lreg[r] += p;
                Pl[16 * w + g * 4 + r][kb * 16 + l15] = f2bf(p);
            }
        }
        __syncthreads();

        bf16x8 pa0 = *(const bf16x8*)&Pl[16 * w + l15][g * 8];
        bf16x8 pa1 = *(const bf16x8*)&Pl[16 * w + l15][g * 8 + 32];
        #pragma unroll
        for (int db = 0; db < 4; ++db) {
            const int row = db * 16 + l15;
            const bf16x8 vb0 = *(const bf16x8*)&Vl[row * 64 + ((g       ^ (row & 7)) * 8)];
            const bf16x8 vb1 = *(const bf16x8*)&Vl[row * 64 + (((g + 4) ^ (row & 7)) * 8)];
            acc_o[db] = __builtin_amdgcn_mfma_f32_16x16x32_bf16(pa0, vb0, acc_o[db], 0, 0, 0);
            acc_o[db] = __builtin_amdgcn_mfma_f32_16x16x32_bf16(pa1, vb1, acc_o[db], 0, 0, 0);
        }

        if (more) {
            #pragma unroll
            for (int i = 0; i < 8; ++i) kc[i] = kn[i];
        }
    }

    #pragma unroll
    for (int r = 0; r < 4; ++r) {
        float l = lreg[r];
        l += __shfl_xor(l, 1);
        l += __shfl_xor(l, 2);
        l += __shfl_xor(l, 4);
        l += __shfl_xor(l, 8);
        float inv = 1.0f / l;
        ushort* op = out + ((size_t)(b * TT + q0 + 16 * w + g * 4 + r)) * DD + h * HSS;
        #pragma unroll
        for (int db = 0; db < 4; ++db)
            op[db * 16 + l15] = f2bf(acc_o[db][r] * inv);
    }
}

// ---------------- combine per-block softmax partials into per-row loss
__global__ __launch_bounds__(256)
void rowloss_finalize(const float* __restrict__ logits, const int* __restrict__ targets,
                      const float* __restrict__ smax, const float* __restrict__ ssum,
                      float* __restrict__ rowloss)
{
    const int wv = threadIdx.x >> 6, lane = threadIdx.x & 63;
    const int row = blockIdx.x * 4 + wv;
    const float* mrow = smax + (size_t)row * NBLK_V;
    const float* srow = ssum + (size_t)row * NBLK_V;
    float M = -1e30f;
    for (int i = lane; i < NBLK_V; i += 64) M = fmaxf(M, mrow[i]);
    #pragma unroll
    for (int off = 32; off; off >>= 1) M = fmaxf(M, __shfl_xor(M, off));
    float S = 0.f;
    for (int i = lane; i < NBLK_V; i += 64) S += srow[i] * __expf(mrow[i] - M);
    #pragma unroll
    for (int off = 32; off; off >>= 1) S += __shfl_xor(S, off);
    if (lane == 0)
        rowloss[row] = -(logits[(size_t)row * VV + targets[row]] - M - logf(S));
}

__global__ __launch_bounds__(256)
void loss_finalize(const float* __restrict__ rowloss, float* __restrict__ out)
{
    __shared__ float red[256];
    float s = 0.f;
    for (int i = threadIdx.x; i < BB * TT; i += 256) s += rowloss[i];
    red[threadIdx.x] = s; __syncthreads();
    for (int s2 = 128; s2; s2 >>= 1) {
        if (threadIdx.x < s2) red[threadIdx.x] += red[threadIdx.x + s2];
        __syncthreads();
    }
    if (threadIdx.x == 0) out[0] = red[0] * (1.0f / (BB * TT));
}

extern "C" void kernel_launch(void* const* d_in, const int* in_sizes, int n_in,
                              void* d_out, int out_size, void* d_ws, size_t ws_size,
                              hipStream_t stream) {
    const int*   idx     = (const int*)  d_in[0];
    const int*   targets = (const int*)  d_in[1];
    const float* tok_emb = (const float*)d_in[2];
    const float* pos_emb = (const float*)d_in[3];
    const float* ln1_g   = (const float*)d_in[4];
    const float* ln1_b   = (const float*)d_in[5];
    const float* Wq      = (const float*)d_in[6];
    const float* Wk      = (const float*)d_in[7];
    const float* Wv      = (const float*)d_in[8];
    const float* Wo      = (const float*)d_in[9];
    const float* bo      = (const float*)d_in[10];
    const float* ln2_g   = (const float*)d_in[11];
    const float* ln2_b   = (const float*)d_in[12];
    const float* W1      = (const float*)d_in[13];
    const float* b1      = (const float*)d_in[14];
    const float* W2      = (const float*)d_in[15];
    const float* b2      = (const float*)d_in[16];
    const float* lnf_g   = (const float*)d_in[17];
    const float* lnf_b   = (const float*)d_in[18];
    const float* Wout    = (const float*)d_in[19];
    const float* bout    = (const float*)d_in[20];

    float* outf   = (float*)d_out;
    float* logits = outf + 1;                   // [B*T, V] fp32

    const size_t ROW = (size_t)BB * TT;         // 4096

    // ---- d_ws: x (fp32) | h_bf | Wout^T (bf16) | rowloss
    float*  x     = (float*)d_ws;
    ushort* h_bf  = (ushort*)(x + ROW * DD);
    ushort* Woutt = h_bf + ROW * DD;
    float*  rowloss = (float*)(Woutt + (size_t)VV * DD);
    float* smax = x;                            // ROW * NBLK_V (x dead by then)
    float* ssum = x + ROW * NBLK_V;

    // ---- scratch inside the (dead-until-final) logits region of d_out
    ushort* sc     = (ushort*)(outf + 8);
    ushort* qkv_bf = sc;                        // ROW*1536
    ushort* ff_bf  = qkv_bf + ROW * 1536;       // ROW*2048
    ushort* Wqkvt  = ff_bf + ROW * FF_;         // L*1536*512
    ushort* Wot    = Wqkvt + (size_t)LL * 1536 * DD;
    ushort* W1t    = Wot   + (size_t)LL * DD * DD;
    ushort* W2t    = W1t   + (size_t)LL * FF_ * DD;
    ushort* vt_g   = W2t   + (size_t)LL * DD * FF_;   // BB*HH*64*TT (4.2 MB)

    qkv_transpose<<<dim3(8, 96), 256, 0, stream>>>(Wq, Wk, Wv, Wqkvt);
    transpose_cvt<<<dim3(8, 8, LL),  256, 0, stream>>>(Wo,   Wot,   DD,  DD,  (long)DD*DD,   (long)DD*DD);
    transpose_cvt<<<dim3(32, 8, LL), 256, 0, stream>>>(W1,   W1t,   FF_, DD,  (long)DD*FF_,  (long)DD*FF_);
    transpose_cvt<<<dim3(8, 32, LL), 256, 0, stream>>>(W2,   W2t,   DD,  FF_, (long)FF_*DD,  (long)FF_*DD);
    transpose_cvt<<<dim3(500, 8, 1), 256, 0, stream>>>(Wout, Woutt, VV,  DD,  0, 0);

    embed_kernel<<<ROW, 64, 0, stream>>>(idx, tok_emb, pos_emb, x);

    for (int l = 0; l < LL; ++l) {
        ln_kernel<<<ROW / 4, 256, 0, stream>>>(x, ln1_g + l * DD, ln1_b + l * DD, h_bf);

        mfma_gemm_db<<<dim3(1536 / 128, ROW / 128), 256, 0, stream>>>(
            h_bf, DD, Wqkvt + (size_t)l * 1536 * DD, DD,
            nullptr, qkv_bf, 1536, nullptr, nullptr, 0, DD, 0);

        v_transpose<<<dim3(TT / 64, BB * HH), 256, 0, stream>>>(qkv_bf, vt_g);

        attn_mfma_kernel<<<dim3(TT / 64, BB * HH), 256, 0, stream>>>(qkv_bf, vt_g, h_bf);

        mfma_gemm_db64<<<dim3(DD / 128, ROW / 64), 256, 0, stream>>>(
            h_bf, DD, Wot + (size_t)l * DD * DD, DD,
            x, nullptr, DD, bo + l * DD, x, DD, DD, 0);

        ln_kernel<<<ROW / 4, 256, 0, stream>>>(x, ln2_g + l * DD, ln2_b + l * DD, h_bf);

        mfma_gemm_db<<<dim3(FF_ / 128, ROW / 128), 256, 0, stream>>>(
            h_bf, DD, W1t + (size_t)l * FF_ * DD, DD,
            nullptr, ff_bf, FF_, b1 + l * FF_, nullptr, 0, DD, 1);

        mfma_gemm_db64<<<dim3(DD / 128, ROW / 64), 256, 0, stream>>>(
            ff_bf, FF_, W2t + (size_t)l * DD * FF_, FF_,
            x, nullptr, DD, b2 + l * DD, x, DD, FF_, 0);
    }

    ln_kernel<<<ROW / 4, 256, 0, stream>>>(x, lnf_g, lnf_b, h_bf);

    // logits GEMM: R16/R18-proven BM=256 BK=64 single-buffer config
    mfma_gemm_logits<<<dim3(VV / 128, ROW / 256), 512, 0, stream>>>(
        h_bf, DD, Woutt, DD,
        logits, VV, bout, DD,
        smax, ssum, NBLK_V);

    rowloss_finalize<<<ROW / 4, 256, 0, stream>>>(logits, targets, smax, ssum, rowloss);
    loss_finalize<<<1, 256, 0, stream>>>(rowloss, outf);
}

// Round 22
// 1222.605 us; speedup vs baseline: 1.1080x; 1.0046x over previous
//
#include <hip/hip_runtime.h>
#include <hip/hip_bf16.h>
#include <math.h>

#define TT 2048
#define BB 2
#define VV 32000
#define DD 512
#define HH 8
#define HSS 64
#define LL 4
#define FF_ 2048
#define NBLK_V (VV / 128)   // 250

using bf16x8 = __attribute__((ext_vector_type(8))) short;
using floatx4 = __attribute__((ext_vector_type(4))) float;

__device__ __forceinline__ ushort f2bf(float f) {
    __hip_bfloat16 b = __float2bfloat16(f);
    return *reinterpret_cast<ushort*>(&b);
}
__device__ __forceinline__ float bf2f(ushort u) {
    union { unsigned int i; float f; } x; x.i = ((unsigned int)u) << 16; return x.f;
}
__device__ __forceinline__ void gload16(const void* g, void* l) {
    __builtin_amdgcn_global_load_lds(
        (const __attribute__((address_space(1))) void*)g,
        (__attribute__((address_space(3))) void*)l, 16, 0, 0);
}

// ---------------- embedding
__global__ __launch_bounds__(64)
void embed_kernel(const int* __restrict__ idx, const float* __restrict__ tok,
                  const float* __restrict__ pos, float* __restrict__ x)
{
    int row = blockIdx.x;
    int t = row & (TT - 1);
    int tokid = idx[row];
    int lane = threadIdx.x;
    const float4* tp = (const float4*)(tok + (size_t)tokid * DD);
    const float4* pp = (const float4*)(pos + (size_t)t * DD);
    float4* xp = (float4*)(x + (size_t)row * DD);
    int i0 = lane * 2;
    float4 a = tp[i0],   b4 = pp[i0];
    float4 c = tp[i0+1], d4 = pp[i0+1];
    xp[i0]   = make_float4(a.x + b4.x, a.y + b4.y, a.z + b4.z, a.w + b4.w);
    xp[i0+1] = make_float4(c.x + d4.x, c.y + d4.y, c.z + d4.z, c.w + d4.w);
}

// ---------------- layernorm -> bf16
__global__ __launch_bounds__(256)
void ln_kernel(const float* __restrict__ x, const float* __restrict__ g,
               const float* __restrict__ b, ushort* __restrict__ out)
{
    int wave = threadIdx.x >> 6;
    int lane = threadIdx.x & 63;
    int row  = blockIdx.x * 4 + wave;
    const float* xr = x + (size_t)row * DD;
    float4 v0 = *(const float4*)(xr + lane * 8);
    float4 v1 = *(const float4*)(xr + lane * 8 + 4);
    float s = v0.x + v0.y + v0.z + v0.w + v1.x + v1.y + v1.z + v1.w;
    float q = v0.x*v0.x + v0.y*v0.y + v0.z*v0.z + v0.w*v0.w
            + v1.x*v1.x + v1.y*v1.y + v1.z*v1.z + v1.w*v1.w;
    #pragma unroll
    for (int off = 32; off; off >>= 1) {
        s += __shfl_xor(s, off);
        q += __shfl_xor(q, off);
    }
    float mu  = s * (1.0f / DD);
    float var = q * (1.0f / DD) - mu * mu;
    float rs  = rsqrtf(var + 1e-5f);
    float4 g0 = *(const float4*)(g + lane * 8);
    float4 g1 = *(const float4*)(g + lane * 8 + 4);
    float4 b0 = *(const float4*)(b + lane * 8);
    float4 b1 = *(const float4*)(b + lane * 8 + 4);
    union { ushort u[8]; uint4 v; } pk;
    pk.u[0] = f2bf((v0.x - mu) * rs * g0.x + b0.x);
    pk.u[1] = f2bf((v0.y - mu) * rs * g0.y + b0.y);
    pk.u[2] = f2bf((v0.z - mu) * rs * g0.z + b0.z);
    pk.u[3] = f2bf((v0.w - mu) * rs * g0.w + b0.w);
    pk.u[4] = f2bf((v1.x - mu) * rs * g1.x + b1.x);
    pk.u[5] = f2bf((v1.y - mu) * rs * g1.y + b1.y);
    pk.u[6] = f2bf((v1.z - mu) * rs * g1.z + b1.z);
    pk.u[7] = f2bf((v1.w - mu) * rs * g1.w + b1.w);
    *(uint4*)(out + (size_t)row * DD + lane * 8) = pk.v;
}

// ---------------- transpose+convert: in [K][N] f32 -> out [N][K] bf16
__global__ __launch_bounds__(256)
void transpose_cvt(const float* __restrict__ in, ushort* __restrict__ out,
                   int N, int K, long inStrideZ, long outStrideZ)
{
    __shared__ float t[64][65];
    in  += (size_t)blockIdx.z * inStrideZ;
    out += (size_t)blockIdx.z * outStrideZ;
    const int n0 = blockIdx.x * 64, k0 = blockIdx.y * 64;
    const int r = threadIdx.x >> 2;
    const int c = (threadIdx.x & 3) * 16;
    #pragma unroll
    for (int j = 0; j < 16; j += 4) {
        float4 v = *(const float4*)&in[(size_t)(k0 + r) * N + n0 + c + j];
        t[r][c + j + 0] = v.x; t[r][c + j + 1] = v.y;
        t[r][c + j + 2] = v.z; t[r][c + j + 3] = v.w;
    }
    __syncthreads();
    union { ushort u[8]; uint4 v; } pk;
    ushort* orow = out + (size_t)(n0 + r) * K + k0 + c;
    #pragma unroll
    for (int half = 0; half < 2; ++half) {
        #pragma unroll
        for (int j = 0; j < 8; ++j) pk.u[j] = f2bf(t[c + half * 8 + j][r]);
        *(uint4*)(orow + half * 8) = pk.v;
    }
}

// ---------------- QKV weights -> fused [L][1536][512] bf16
__global__ __launch_bounds__(256)
void qkv_transpose(const float* __restrict__ Wq, const float* __restrict__ Wk,
                   const float* __restrict__ Wv, ushort* __restrict__ out)
{
    __shared__ float t[64][65];
    const int z = blockIdx.y;
    const int sel = z >> 5, l = (z >> 3) & 3, h = z & 7;
    const float* in = (sel == 0 ? Wq : sel == 1 ? Wk : Wv)
                      + (size_t)l * (HH * DD * HSS) + (size_t)h * (DD * HSS);
    ushort* ob = out + (size_t)l * (3 * DD * DD) + (size_t)sel * (DD * DD)
                     + (size_t)h * (HSS * DD);
    const int d0 = blockIdx.x * 64;
    const int r = threadIdx.x >> 2;
    const int c = (threadIdx.x & 3) * 16;
    #pragma unroll
    for (int j = 0; j < 16; j += 4) {
        float4 v = *(const float4*)&in[(size_t)(d0 + r) * HSS + c + j];
        t[r][c + j + 0] = v.x; t[r][c + j + 1] = v.y;
        t[r][c + j + 2] = v.z; t[r][c + j + 3] = v.w;
    }
    __syncthreads();
    union { ushort u[8]; uint4 v; } pk;
    ushort* orow = ob + (size_t)r * DD + d0 + c;
    #pragma unroll
    for (int half = 0; half < 2; ++half) {
        #pragma unroll
        for (int j = 0; j < 8; ++j) pk.u[j] = f2bf(t[c + half * 8 + j][r]);
        *(uint4*)(orow + half * 8) = pk.v;
    }
}

// ---------------- logits GEMM: BM=256 x BN=128, BK=64, single-buffer
// R16-proven Pareto point: 284 MB fetch, 42% occupancy, ~316 us.
__global__ __launch_bounds__(512, 2)
void mfma_gemm_logits(const ushort* __restrict__ A, int lda,
                      const ushort* __restrict__ Bt, int ldb,
                      float* __restrict__ Cf, int ldc,
                      const float* __restrict__ bias,
                      int K,
                      float* __restrict__ smax, float* __restrict__ ssum, int nblks)
{
    __shared__ ushort As[32 * 512];
    __shared__ ushort Bs[16 * 512];
    __shared__ float sstat[2][256][2];

    const int bxx = blockIdx.x, byy = blockIdx.y;
    const int m0 = byy << 8, n0 = bxx << 7;
    const int tid = threadIdx.x, w = tid >> 6, lane = tid & 63;
    const int wm = w >> 1, wn = w & 1;
    const int l15 = lane & 15, lk = lane >> 4;

    floatx4 acc[4][4] = {};

    for (int k0 = 0; k0 < K; k0 += 64) {
        #pragma unroll
        for (int i = 0; i < 4; ++i) {
            int c = 4 * w + i;
            int cg = c >> 1, ckh = c & 1;
            gload16(A + (size_t)(m0 + cg * 16 + l15) * lda + k0 + lk * 8 + ckh * 32,
                    &As[c * 512]);
        }
        #pragma unroll
        for (int i = 0; i < 2; ++i) {
            int c = 2 * w + i;
            int cg = c >> 1, ckh = c & 1;
            gload16(Bt + (size_t)(n0 + cg * 16 + l15) * ldb + k0 + lk * 8 + ckh * 32,
                    &Bs[c * 512]);
        }
        __syncthreads();
        #pragma unroll
        for (int kh = 0; kh < 2; ++kh) {
            bf16x8 af[4], bfr[4];
            #pragma unroll
            for (int mi = 0; mi < 4; ++mi)
                af[mi] = *(const bf16x8*)&As[(((wm * 4 + mi) * 2 + kh) * 64 + lane) * 8];
            #pragma unroll
            for (int ni = 0; ni < 4; ++ni)
                bfr[ni] = *(const bf16x8*)&Bs[(((wn * 4 + ni) * 2 + kh) * 64 + lane) * 8];
            #pragma unroll
            for (int mi = 0; mi < 4; ++mi)
                #pragma unroll
                for (int ni = 0; ni < 4; ++ni)
                    acc[mi][ni] = __builtin_amdgcn_mfma_f32_16x16x32_bf16(
                        af[mi], bfr[ni], acc[mi][ni], 0, 0, 0);
        }
        __syncthreads();
    }

    #pragma unroll
    for (int mi = 0; mi < 4; ++mi)
        #pragma unroll
        for (int ni = 0; ni < 4; ++ni) {
            float bv = bias[n0 + wn * 64 + ni * 16 + l15];
            #pragma unroll
            for (int r = 0; r < 4; ++r) acc[mi][ni][r] += bv;
        }

    #pragma unroll
    for (int mi = 0; mi < 4; ++mi) {
        #pragma unroll
        for (int r = 0; r < 4; ++r) {
            int grow = m0 + wm * 64 + mi * 16 + lk * 4 + r;
            #pragma unroll
            for (int ni = 0; ni < 4; ++ni)
                Cf[(size_t)grow * ldc + n0 + wn * 64 + ni * 16 + l15] = acc[mi][ni][r];
        }
    }

    #pragma unroll
    for (int mi = 0; mi < 4; ++mi) {
        #pragma unroll
        for (int r = 0; r < 4; ++r) {
            float m4 = fmaxf(fmaxf(acc[mi][0][r], acc[mi][1][r]),
                             fmaxf(acc[mi][2][r], acc[mi][3][r]));
            m4 = fmaxf(m4, __shfl_xor(m4, 1));
            m4 = fmaxf(m4, __shfl_xor(m4, 2));
            m4 = fmaxf(m4, __shfl_xor(m4, 4));
            m4 = fmaxf(m4, __shfl_xor(m4, 8));
            float s4 = 0.f;
            #pragma unroll
            for (int ni = 0; ni < 4; ++ni) s4 += __expf(acc[mi][ni][r] - m4);
            s4 += __shfl_xor(s4, 1);
            s4 += __shfl_xor(s4, 2);
            s4 += __shfl_xor(s4, 4);
            s4 += __shfl_xor(s4, 8);
            if (l15 == 0) {
                int R = wm * 64 + mi * 16 + lk * 4 + r;
                sstat[0][R][wn] = m4;
                sstat[1][R][wn] = s4;
            }
        }
    }
    __syncthreads();
    if (tid < 256) {
        float ma = sstat[0][tid][0], mb = sstat[0][tid][1];
        float M = fmaxf(ma, mb);
        float S = sstat[1][tid][0] * __expf(ma - M)
                + sstat[1][tid][1] * __expf(mb - M);
        smax[(size_t)(m0 + tid) * nblks + bxx] = M;
        ssum[(size_t)(m0 + tid) * nblks + bxx] = S;
    }
}

// ---------------- layer GEMM 128x128: counted-vmcnt double-buffer (T3/T4)
// vt non-null (QKV only): V-region tiles (n0 >= 1024) are written TRANSPOSED
// to vt[bh][d][T] via an LDS-staged coalesced epilogue (replaces v_transpose).
__global__ __launch_bounds__(256, 2)
void mfma_gemm_db(const ushort* __restrict__ A, int lda,
                  const ushort* __restrict__ Bt, int ldb,
                  float* __restrict__ Cf, ushort* __restrict__ Cbf, int ldc,
                  const float* __restrict__ bias,
                  const float* __restrict__ resid, int ldres,
                  int K, int relu, ushort* __restrict__ vt)
{
    __shared__ ushort st[2][2][8192];   // [buf][A|B] = 64 KB

    const int m0 = blockIdx.y << 7, n0 = blockIdx.x << 7;
    const int tid = threadIdx.x, w = tid >> 6, lane = tid & 63;
    const int wm = w >> 1, wn = w & 1;
    const int l15 = lane & 15, lk = lane >> 4;
    const int nt = K >> 6;

    auto STAGE = [&](int t, int p) {
        const int k0 = t << 6;
        #pragma unroll
        for (int i = 0; i < 4; ++i) {
            int c = 4 * w + i;
            int cg = c >> 3, cmi = (c >> 1) & 3, ckh = c & 1;
            gload16(A + (size_t)(m0 + cg * 64 + cmi * 16 + l15) * lda
                      + k0 + lk * 8 + ckh * 32, &st[p][0][c * 512]);
            gload16(Bt + (size_t)(n0 + cg * 64 + cmi * 16 + l15) * ldb
                       + k0 + lk * 8 + ckh * 32, &st[p][1][c * 512]);
        }
    };

    floatx4 acc[4][4] = {};
    STAGE(0, 0);

    for (int t = 0; t < nt; ++t) {
        const int p = t & 1;
        if (t + 1 < nt) {
            STAGE(t + 1, p ^ 1);
            asm volatile("s_waitcnt vmcnt(8)" ::: "memory");
        } else {
            asm volatile("s_waitcnt vmcnt(0)" ::: "memory");
        }
        __builtin_amdgcn_s_barrier();
        __builtin_amdgcn_sched_barrier(0);
        #pragma unroll
        for (int kh = 0; kh < 2; ++kh) {
            bf16x8 af[4], bfr[4];
            #pragma unroll
            for (int mi = 0; mi < 4; ++mi)
                af[mi] = *(const bf16x8*)&st[p][0][((wm * 8 + mi * 2 + kh) * 64 + lane) * 8];
            #pragma unroll
            for (int ni = 0; ni < 4; ++ni)
                bfr[ni] = *(const bf16x8*)&st[p][1][((wn * 8 + ni * 2 + kh) * 64 + lane) * 8];
            #pragma unroll
            for (int mi = 0; mi < 4; ++mi)
                #pragma unroll
                for (int ni = 0; ni < 4; ++ni)
                    acc[mi][ni] = __builtin_amdgcn_mfma_f32_16x16x32_bf16(
                        af[mi], bfr[ni], acc[mi][ni], 0, 0, 0);
        }
        __builtin_amdgcn_sched_barrier(0);
        __builtin_amdgcn_s_barrier();
    }

    #pragma unroll
    for (int mi = 0; mi < 4; ++mi)
        #pragma unroll
        for (int ni = 0; ni < 4; ++ni)
            #pragma unroll
            for (int r = 0; r < 4; ++r) {
                float v = acc[mi][ni][r];
                if (bias) v += bias[n0 + wn * 64 + ni * 16 + l15];
                if (relu) v = fmaxf(v, 0.0f);
                acc[mi][ni][r] = v;
            }

    if (vt && n0 >= 1024) {
        // ---- fused V-transpose epilogue: stage bf16 tile in (free) LDS,
        //      write coalesced along T to vt[bh][d][T]
        ushort* Ls = &st[0][0][0];          // 128 x 136 layout (34.8 KB < 64 KB)
        #pragma unroll
        for (int mi = 0; mi < 4; ++mi)
            #pragma unroll
            for (int r = 0; r < 4; ++r) {
                int lrow = wm * 64 + mi * 16 + lk * 4 + r;
                #pragma unroll
                for (int ni = 0; ni < 4; ++ni)
                    Ls[lrow * 136 + wn * 64 + ni * 16 + l15] = f2bf(acc[mi][ni][r]);
            }
        __syncthreads();
        const int b = m0 >> 11, tbase = m0 & 2047;
        const int h0 = (n0 - 1024) >> 6;    // first head in this tile
        const int dr = tid >> 1;            // local col 0..127
        const int half = tid & 1;           // t-half 0/1
        const int z = b * HH + h0 + (dr >> 6);
        const int d = dr & 63;
        ushort* dst = vt + ((size_t)z * 64 + d) * TT + tbase + half * 64;
        #pragma unroll
        for (int j = 0; j < 8; ++j) {
            union { ushort u[8]; uint4 v; } pk;
            #pragma unroll
            for (int e = 0; e < 8; ++e)
                pk.u[e] = Ls[(half * 64 + j * 8 + e) * 136 + dr];
            *(uint4*)(dst + j * 8) = pk.v;
        }
        return;
    }

    #pragma unroll
    for (int mi = 0; mi < 4; ++mi) {
        #pragma unroll
        for (int r = 0; r < 4; ++r) {
            int grow = m0 + wm * 64 + mi * 16 + lk * 4 + r;
            #pragma unroll
            for (int ni = 0; ni < 4; ++ni) {
                int gcol = n0 + wn * 64 + ni * 16 + l15;
                float v = acc[mi][ni][r];
                if (resid) v += resid[(size_t)grow * ldres + gcol];
                if (Cbf) Cbf[(size_t)grow * ldc + gcol] = f2bf(v);
                else     Cf [(size_t)grow * ldc + gcol] = v;
            }
        }
    }
}

// ---------------- layer GEMM 64x128 (for N=512 outputs: 256-block grids)
__global__ __launch_bounds__(256, 3)
void mfma_gemm_db64(const ushort* __restrict__ A, int lda,
                    const ushort* __restrict__ Bt, int ldb,
                    float* __restrict__ Cf, ushort* __restrict__ Cbf, int ldc,
                    const float* __restrict__ bias,
                    const float* __restrict__ resid, int ldres,
                    int K, int relu)
{
    __shared__ ushort stA[2][8 * 512];
    __shared__ ushort stB[2][16 * 512];

    const int m0 = blockIdx.y << 6, n0 = blockIdx.x << 7;
    const int tid = threadIdx.x, w = tid >> 6, lane = tid & 63;
    const int l15 = lane & 15, lk = lane >> 4;
    const int nt = K >> 6;

    auto STAGE = [&](int t, int p) {
        const int k0 = t << 6;
        #pragma unroll
        for (int i = 0; i < 2; ++i) {
            int c = 2 * w + i;
            int cmi = c >> 1, ckh = c & 1;
            gload16(A + (size_t)(m0 + cmi * 16 + l15) * lda
                      + k0 + lk * 8 + ckh * 32, &stA[p][c * 512]);
        }
        #pragma unroll
        for (int i = 0; i < 4; ++i) {
            int c = 4 * w + i;
            int cnj = c >> 1, ckh = c & 1;
            gload16(Bt + (size_t)(n0 + cnj * 16 + l15) * ldb
                       + k0 + lk * 8 + ckh * 32, &stB[p][c * 512]);
        }
    };

    floatx4 acc[4][2] = {};
    STAGE(0, 0);

    for (int t = 0; t < nt; ++t) {
        const int p = t & 1;
        if (t + 1 < nt) {
            STAGE(t + 1, p ^ 1);
            asm volatile("s_waitcnt vmcnt(6)" ::: "memory");
        } else {
            asm volatile("s_waitcnt vmcnt(0)" ::: "memory");
        }
        __builtin_amdgcn_s_barrier();
        __builtin_amdgcn_sched_barrier(0);
        #pragma unroll
        for (int kh = 0; kh < 2; ++kh) {
            bf16x8 af[4], bfr[2];
            #pragma unroll
            for (int mi = 0; mi < 4; ++mi)
                af[mi] = *(const bf16x8*)&stA[p][((mi * 2 + kh) * 64 + lane) * 8];
            #pragma unroll
            for (int ni = 0; ni < 2; ++ni)
                bfr[ni] = *(const bf16x8*)&stB[p][(((w * 2 + ni) * 2 + kh) * 64 + lane) * 8];
            #pragma unroll
            for (int mi = 0; mi < 4; ++mi)
                #pragma unroll
                for (int ni = 0; ni < 2; ++ni)
                    acc[mi][ni] = __builtin_amdgcn_mfma_f32_16x16x32_bf16(
                        af[mi], bfr[ni], acc[mi][ni], 0, 0, 0);
        }
        __builtin_amdgcn_sched_barrier(0);
        __builtin_amdgcn_s_barrier();
    }

    #pragma unroll
    for (int mi = 0; mi < 4; ++mi)
        #pragma unroll
        for (int ni = 0; ni < 2; ++ni)
            #pragma unroll
            for (int r = 0; r < 4; ++r) {
                float v = acc[mi][ni][r];
                if (bias) v += bias[n0 + w * 32 + ni * 16 + l15];
                if (relu) v = fmaxf(v, 0.0f);
                acc[mi][ni][r] = v;
            }

    #pragma unroll
    for (int mi = 0; mi < 4; ++mi) {
        #pragma unroll
        for (int r = 0; r < 4; ++r) {
            int grow = m0 + mi * 16 + lk * 4 + r;
            #pragma unroll
            for (int ni = 0; ni < 2; ++ni) {
                int gcol = n0 + w * 32 + ni * 16 + l15;
                float v = acc[mi][ni][r];
                if (resid) v += resid[(size_t)grow * ldres + gcol];
                if (Cbf) Cbf[(size_t)grow * ldc + gcol] = f2bf(v);
                else     Cf [(size_t)grow * ldc + gcol] = v;
            }
        }
    }
}

// ---------------- MFMA flash attention (V via gload_lds, K reg-prefetch)
__global__ __launch_bounds__(256)
void attn_mfma_kernel(const ushort* __restrict__ qkv, const ushort* __restrict__ vt,
                      ushort* __restrict__ out)
{
    __shared__ ushort Vl[64 * 64];   // [d][key] linear, swizzled content (8 KB)
    __shared__ ushort Pl[64][72];    // P[q_local][key]

    const int z = blockIdx.y, b = z >> 3, h = z & 7;
    const int q0 = blockIdx.x << 6;
    const int tid = threadIdx.x;
    const int w = tid >> 6, lane = tid & 63;
    const int l15 = lane & 15, g = lane >> 4;
    const float scale = 0.04419417382415922f;  // 1/sqrt(512)
    const ushort* vbase = vt + (size_t)z * 64 * TT;

    bf16x8 qf0, qf1;
    {
        const ushort* qp = qkv + ((size_t)(b * TT + q0 + 16 * w + l15)) * 1536
                               + h * HSS + g * 8;
        qf0 = *(const bf16x8*)qp;
        qf1 = *(const bf16x8*)(qp + 32);
    }

    bf16x8 kc[8], kn[8];
    {
        #pragma unroll
        for (int kb = 0; kb < 4; ++kb) {
            const ushort* kp = qkv + ((size_t)(b * TT + kb * 16 + l15)) * 1536
                                   + 512 + h * HSS + g * 8;
            kc[kb * 2]     = *(const bf16x8*)kp;
            kc[kb * 2 + 1] = *(const bf16x8*)(kp + 32);
        }
    }

    floatx4 acc_o[4] = {};
    float lreg[4] = {};

    for (int s0 = 0; s0 <= q0; s0 += 64) {
        __syncthreads();
        #pragma unroll
        for (int i = 0; i < 2; ++i) {
            const int cbase = (w * 2 + i) * 64;
            const int c = cbase + lane;
            const int row = c >> 3;
            const int kg = (c & 7) ^ (row & 7);
            gload16(vbase + (size_t)row * TT + s0 + kg * 8, &Vl[cbase * 8]);
        }

        floatx4 s4[4] = {};
        #pragma unroll
        for (int kb = 0; kb < 4; ++kb) {
            s4[kb] = __builtin_amdgcn_mfma_f32_16x16x32_bf16(qf0, kc[kb*2],   s4[kb], 0, 0, 0);
            s4[kb] = __builtin_amdgcn_mfma_f32_16x16x32_bf16(qf1, kc[kb*2+1], s4[kb], 0, 0, 0);
        }

        const bool more = (s0 + 64 <= q0);
        if (more) {
            #pragma unroll
            for (int kb = 0; kb < 4; ++kb) {
                const ushort* kp = qkv + ((size_t)(b * TT + s0 + 64 + kb * 16 + l15)) * 1536
                                       + 512 + h * HSS + g * 8;
                kn[kb * 2]     = *(const bf16x8*)kp;
                kn[kb * 2 + 1] = *(const bf16x8*)(kp + 32);
            }
        }

        const bool diag = (s0 == q0);
        #pragma unroll
        for (int r = 0; r < 4; ++r) {
            const int qrow = q0 + 16 * w + g * 4 + r;
            #pragma unroll
            for (int kb = 0; kb < 4; ++kb) {
                float xs = s4[kb][r] * scale;
                if (diag && (s0 + kb * 16 + l15) > qrow) xs = -1e30f;
                float p = __expf(xs);
                lreg[r] += p;
                Pl[16 * w + g * 4 + r][kb * 16 + l15] = f2bf(p);
            }
        }
        __syncthreads();

        bf16x8 pa0 = *(const bf16x8*)&Pl[16 * w + l15][g * 8];
        bf16x8 pa1 = *(const bf16x8*)&Pl[16 * w + l15][g * 8 + 32];
        #pragma unroll
        for (int db = 0; db < 4; ++db) {
            const int row = db * 16 + l15;
            const bf16x8 vb0 = *(const bf16x8*)&Vl[row * 64 + ((g       ^ (row & 7)) * 8)];
            const bf16x8 vb1 = *(const bf16x8*)&Vl[row * 64 + (((g + 4) ^ (row & 7)) * 8)];
            acc_o[db] = __builtin_amdgcn_mfma_f32_16x16x32_bf16(pa0, vb0, acc_o[db], 0, 0, 0);
            acc_o[db] = __builtin_amdgcn_mfma_f32_16x16x32_bf16(pa1, vb1, acc_o[db], 0, 0, 0);
        }

        if (more) {
            #pragma unroll
            for (int i = 0; i < 8; ++i) kc[i] = kn[i];
        }
    }

    #pragma unroll
    for (int r = 0; r < 4; ++r) {
        float l = lreg[r];
        l += __shfl_xor(l, 1);
        l += __shfl_xor(l, 2);
        l += __shfl_xor(l, 4);
        l += __shfl_xor(l, 8);
        float inv = 1.0f / l;
        ushort* op = out + ((size_t)(b * TT + q0 + 16 * w + g * 4 + r)) * DD + h * HSS;
        #pragma unroll
        for (int db = 0; db < 4; ++db)
            op[db * 16 + l15] = f2bf(acc_o[db][r] * inv);
    }
}

// ---------------- combine per-block softmax partials into per-row loss
__global__ __launch_bounds__(256)
void rowloss_finalize(const float* __restrict__ logits, const int* __restrict__ targets,
                      const float* __restrict__ smax, const float* __restrict__ ssum,
                      float* __restrict__ rowloss)
{
    const int wv = threadIdx.x >> 6, lane = threadIdx.x & 63;
    const int row = blockIdx.x * 4 + wv;
    const float* mrow = smax + (size_t)row * NBLK_V;
    const float* srow = ssum + (size_t)row * NBLK_V;
    float M = -1e30f;
    for (int i = lane; i < NBLK_V; i += 64) M = fmaxf(M, mrow[i]);
    #pragma unroll
    for (int off = 32; off; off >>= 1) M = fmaxf(M, __shfl_xor(M, off));
    float S = 0.f;
    for (int i = lane; i < NBLK_V; i += 64) S += srow[i] * __expf(mrow[i] - M);
    #pragma unroll
    for (int off = 32; off; off >>= 1) S += __shfl_xor(S, off);
    if (lane == 0)
        rowloss[row] = -(logits[(size_t)row * VV + targets[row]] - M - logf(S));
}

__global__ __launch_bounds__(256)
void loss_finalize(const float* __restrict__ rowloss, float* __restrict__ out)
{
    __shared__ float red[256];
    float s = 0.f;
    for (int i = threadIdx.x; i < BB * TT; i += 256) s += rowloss[i];
    red[threadIdx.x] = s; __syncthreads();
    for (int s2 = 128; s2; s2 >>= 1) {
        if (threadIdx.x < s2) red[threadIdx.x] += red[threadIdx.x + s2];
        __syncthreads();
    }
    if (threadIdx.x == 0) out[0] = red[0] * (1.0f / (BB * TT));
}

extern "C" void kernel_launch(void* const* d_in, const int* in_sizes, int n_in,
                              void* d_out, int out_size, void* d_ws, size_t ws_size,
                              hipStream_t stream) {
    const int*   idx     = (const int*)  d_in[0];
    const int*   targets = (const int*)  d_in[1];
    const float* tok_emb = (const float*)d_in[2];
    const float* pos_emb = (const float*)d_in[3];
    const float* ln1_g   = (const float*)d_in[4];
    const float* ln1_b   = (const float*)d_in[5];
    const float* Wq      = (const float*)d_in[6];
    const float* Wk      = (const float*)d_in[7];
    const float* Wv      = (const float*)d_in[8];
    const float* Wo      = (const float*)d_in[9];
    const float* bo      = (const float*)d_in[10];
    const float* ln2_g   = (const float*)d_in[11];
    const float* ln2_b   = (const float*)d_in[12];
    const float* W1      = (const float*)d_in[13];
    const float* b1      = (const float*)d_in[14];
    const float* W2      = (const float*)d_in[15];
    const float* b2      = (const float*)d_in[16];
    const float* lnf_g   = (const float*)d_in[17];
    const float* lnf_b   = (const float*)d_in[18];
    const float* Wout    = (const float*)d_in[19];
    const float* bout    = (const float*)d_in[20];

    float* outf   = (float*)d_out;
    float* logits = outf + 1;                   // [B*T, V] fp32

    const size_t ROW = (size_t)BB * TT;         // 4096

    // ---- d_ws: x (fp32) | h_bf | Wout^T (bf16) | rowloss
    float*  x     = (float*)d_ws;
    ushort* h_bf  = (ushort*)(x + ROW * DD);
    ushort* Woutt = h_bf + ROW * DD;
    float*  rowloss = (float*)(Woutt + (size_t)VV * DD);
    float* smax = x;                            // ROW * NBLK_V (x dead by then)
    float* ssum = x + ROW * NBLK_V;

    // ---- scratch inside the (dead-until-final) logits region of d_out
    ushort* sc     = (ushort*)(outf + 8);
    ushort* qkv_bf = sc;                        // ROW*1536
    ushort* ff_bf  = qkv_bf + ROW * 1536;       // ROW*2048
    ushort* Wqkvt  = ff_bf + ROW * FF_;         // L*1536*512
    ushort* Wot    = Wqkvt + (size_t)LL * 1536 * DD;
    ushort* W1t    = Wot   + (size_t)LL * DD * DD;
    ushort* W2t    = W1t   + (size_t)LL * FF_ * DD;
    ushort* vt_g   = W2t   + (size_t)LL * DD * FF_;   // BB*HH*64*TT (4.2 MB)

    qkv_transpose<<<dim3(8, 96), 256, 0, stream>>>(Wq, Wk, Wv, Wqkvt);
    transpose_cvt<<<dim3(8, 8, LL),  256, 0, stream>>>(Wo,   Wot,   DD,  DD,  (long)DD*DD,   (long)DD*DD);
    transpose_cvt<<<dim3(32, 8, LL), 256, 0, stream>>>(W1,   W1t,   FF_, DD,  (long)DD*FF_,  (long)DD*FF_);
    transpose_cvt<<<dim3(8, 32, LL), 256, 0, stream>>>(W2,   W2t,   DD,  FF_, (long)FF_*DD,  (long)FF_*DD);
    transpose_cvt<<<dim3(500, 8, 1), 256, 0, stream>>>(Wout, Woutt, VV,  DD,  0, 0);

    embed_kernel<<<ROW, 64, 0, stream>>>(idx, tok_emb, pos_emb, x);

    for (int l = 0; l < LL; ++l) {
        ln_kernel<<<ROW / 4, 256, 0, stream>>>(x, ln1_g + l * DD, ln1_b + l * DD, h_bf);

        // QKV GEMM with fused V-transpose epilogue (V tiles -> vt_g directly)
        mfma_gemm_db<<<dim3(1536 / 128, ROW / 128), 256, 0, stream>>>(
            h_bf, DD, Wqkvt + (size_t)l * 1536 * DD, DD,
            nullptr, qkv_bf, 1536, nullptr, nullptr, 0, DD, 0, vt_g);

        attn_mfma_kernel<<<dim3(TT / 64, BB * HH), 256, 0, stream>>>(qkv_bf, vt_g, h_bf);

        mfma_gemm_db64<<<dim3(DD / 128, ROW / 64), 256, 0, stream>>>(
            h_bf, DD, Wot + (size_t)l * DD * DD, DD,
            x, nullptr, DD, bo + l * DD, x, DD, DD, 0);

        ln_kernel<<<ROW / 4, 256, 0, stream>>>(x, ln2_g + l * DD, ln2_b + l * DD, h_bf);

        mfma_gemm_db<<<dim3(FF_ / 128, ROW / 128), 256, 0, stream>>>(
            h_bf, DD, W1t + (size_t)l * FF_ * DD, DD,
            nullptr, ff_bf, FF_, b1 + l * FF_, nullptr, 0, DD, 1, nullptr);

        mfma_gemm_db64<<<dim3(DD / 128, ROW / 64), 256, 0, stream>>>(
            ff_bf, FF_, W2t + (size_t)l * DD * FF_, FF_,
            x, nullptr, DD, b2 + l * DD, x, DD, FF_, 0);
    }

    ln_kernel<<<ROW / 4, 256, 0, stream>>>(x, lnf_g, lnf_b, h_bf);

    mfma_gemm_logits<<<dim3(VV / 128, ROW / 256), 512, 0, stream>>>(
        h_bf, DD, Woutt, DD,
        logits, VV, bout, DD,
        smax, ssum, NBLK_V);

    rowloss_finalize<<<ROW / 4, 256, 0, stream>>>(logits, targets, smax, ssum, rowloss);
    loss_finalize<<<1, 256, 0, stream>>>(rowloss, outf);
}

// Round 23
// 1165.141 us; speedup vs baseline: 1.1627x; 1.0493x over previous
//
#include <hip/hip_runtime.h>
#include <hip/hip_bf16.h>
#include <math.h>

#define TT 2048
#define BB 2
#define VV 32000
#define DD 512
#define HH 8
#define HSS 64
#define LL 4
#define FF_ 2048
#define NBLK_V (VV / 128)   // 250

using bf16x8 = __attribute__((ext_vector_type(8))) short;
using floatx4 = __attribute__((ext_vector_type(4))) float;

__device__ __forceinline__ ushort f2bf(float f) {
    __hip_bfloat16 b = __float2bfloat16(f);
    return *reinterpret_cast<ushort*>(&b);
}
__device__ __forceinline__ float bf2f(ushort u) {
    union { unsigned int i; float f; } x; x.i = ((unsigned int)u) << 16; return x.f;
}
__device__ __forceinline__ void gload16(const void* g, void* l) {
    __builtin_amdgcn_global_load_lds(
        (const __attribute__((address_space(1))) void*)g,
        (__attribute__((address_space(3))) void*)l, 16, 0, 0);
}

// ---------------- embedding
__global__ __launch_bounds__(64)
void embed_kernel(const int* __restrict__ idx, const float* __restrict__ tok,
                  const float* __restrict__ pos, float* __restrict__ x)
{
    int row = blockIdx.x;
    int t = row & (TT - 1);
    int tokid = idx[row];
    int lane = threadIdx.x;
    const float4* tp = (const float4*)(tok + (size_t)tokid * DD);
    const float4* pp = (const float4*)(pos + (size_t)t * DD);
    float4* xp = (float4*)(x + (size_t)row * DD);
    int i0 = lane * 2;
    float4 a = tp[i0],   b4 = pp[i0];
    float4 c = tp[i0+1], d4 = pp[i0+1];
    xp[i0]   = make_float4(a.x + b4.x, a.y + b4.y, a.z + b4.z, a.w + b4.w);
    xp[i0+1] = make_float4(c.x + d4.x, c.y + d4.y, c.z + d4.z, c.w + d4.w);
}

// ---------------- layernorm -> bf16
__global__ __launch_bounds__(256)
void ln_kernel(const float* __restrict__ x, const float* __restrict__ g,
               const float* __restrict__ b, ushort* __restrict__ out)
{
    int wave = threadIdx.x >> 6;
    int lane = threadIdx.x & 63;
    int row  = blockIdx.x * 4 + wave;
    const float* xr = x + (size_t)row * DD;
    float4 v0 = *(const float4*)(xr + lane * 8);
    float4 v1 = *(const float4*)(xr + lane * 8 + 4);
    float s = v0.x + v0.y + v0.z + v0.w + v1.x + v1.y + v1.z + v1.w;
    float q = v0.x*v0.x + v0.y*v0.y + v0.z*v0.z + v0.w*v0.w
            + v1.x*v1.x + v1.y*v1.y + v1.z*v1.z + v1.w*v1.w;
    #pragma unroll
    for (int off = 32; off; off >>= 1) {
        s += __shfl_xor(s, off);
        q += __shfl_xor(q, off);
    }
    float mu  = s * (1.0f / DD);
    float var = q * (1.0f / DD) - mu * mu;
    float rs  = rsqrtf(var + 1e-5f);
    float4 g0 = *(const float4*)(g + lane * 8);
    float4 g1 = *(const float4*)(g + lane * 8 + 4);
    float4 b0 = *(const float4*)(b + lane * 8);
    float4 b1 = *(const float4*)(b + lane * 8 + 4);
    union { ushort u[8]; uint4 v; } pk;
    pk.u[0] = f2bf((v0.x - mu) * rs * g0.x + b0.x);
    pk.u[1] = f2bf((v0.y - mu) * rs * g0.y + b0.y);
    pk.u[2] = f2bf((v0.z - mu) * rs * g0.z + b0.z);
    pk.u[3] = f2bf((v0.w - mu) * rs * g0.w + b0.w);
    pk.u[4] = f2bf((v1.x - mu) * rs * g1.x + b1.x);
    pk.u[5] = f2bf((v1.y - mu) * rs * g1.y + b1.y);
    pk.u[6] = f2bf((v1.z - mu) * rs * g1.z + b1.z);
    pk.u[7] = f2bf((v1.w - mu) * rs * g1.w + b1.w);
    *(uint4*)(out + (size_t)row * DD + lane * 8) = pk.v;
}

// ---------------- transpose+convert: in [K][N] f32 -> out [N][K] bf16
__global__ __launch_bounds__(256)
void transpose_cvt(const float* __restrict__ in, ushort* __restrict__ out,
                   int N, int K, long inStrideZ, long outStrideZ)
{
    __shared__ float t[64][65];
    in  += (size_t)blockIdx.z * inStrideZ;
    out += (size_t)blockIdx.z * outStrideZ;
    const int n0 = blockIdx.x * 64, k0 = blockIdx.y * 64;
    const int r = threadIdx.x >> 2;
    const int c = (threadIdx.x & 3) * 16;
    #pragma unroll
    for (int j = 0; j < 16; j += 4) {
        float4 v = *(const float4*)&in[(size_t)(k0 + r) * N + n0 + c + j];
        t[r][c + j + 0] = v.x; t[r][c + j + 1] = v.y;
        t[r][c + j + 2] = v.z; t[r][c + j + 3] = v.w;
    }
    __syncthreads();
    union { ushort u[8]; uint4 v; } pk;
    ushort* orow = out + (size_t)(n0 + r) * K + k0 + c;
    #pragma unroll
    for (int half = 0; half < 2; ++half) {
        #pragma unroll
        for (int j = 0; j < 8; ++j) pk.u[j] = f2bf(t[c + half * 8 + j][r]);
        *(uint4*)(orow + half * 8) = pk.v;
    }
}

// ---------------- QKV weights -> fused [L][1536][512] bf16
__global__ __launch_bounds__(256)
void qkv_transpose(const float* __restrict__ Wq, const float* __restrict__ Wk,
                   const float* __restrict__ Wv, ushort* __restrict__ out)
{
    __shared__ float t[64][65];
    const int z = blockIdx.y;
    const int sel = z >> 5, l = (z >> 3) & 3, h = z & 7;
    const float* in = (sel == 0 ? Wq : sel == 1 ? Wk : Wv)
                      + (size_t)l * (HH * DD * HSS) + (size_t)h * (DD * HSS);
    ushort* ob = out + (size_t)l * (3 * DD * DD) + (size_t)sel * (DD * DD)
                     + (size_t)h * (HSS * DD);
    const int d0 = blockIdx.x * 64;
    const int r = threadIdx.x >> 2;
    const int c = (threadIdx.x & 3) * 16;
    #pragma unroll
    for (int j = 0; j < 16; j += 4) {
        float4 v = *(const float4*)&in[(size_t)(d0 + r) * HSS + c + j];
        t[r][c + j + 0] = v.x; t[r][c + j + 1] = v.y;
        t[r][c + j + 2] = v.z; t[r][c + j + 3] = v.w;
    }
    __syncthreads();
    union { ushort u[8]; uint4 v; } pk;
    ushort* orow = ob + (size_t)r * DD + d0 + c;
    #pragma unroll
    for (int half = 0; half < 2; ++half) {
        #pragma unroll
        for (int j = 0; j < 8; ++j) pk.u[j] = f2bf(t[c + half * 8 + j][r]);
        *(uint4*)(orow + half * 8) = pk.v;
    }
}

// ---------------- logits GEMM: BM=256 x BN=128, BK=64, single-buffer
__global__ __launch_bounds__(512, 2)
void mfma_gemm_logits(const ushort* __restrict__ A, int lda,
                      const ushort* __restrict__ Bt, int ldb,
                      float* __restrict__ Cf, int ldc,
                      const float* __restrict__ bias,
                      int K,
                      float* __restrict__ smax, float* __restrict__ ssum, int nblks)
{
    __shared__ ushort As[32 * 512];
    __shared__ ushort Bs[16 * 512];
    __shared__ float sstat[2][256][2];

    const int bxx = blockIdx.x, byy = blockIdx.y;
    const int m0 = byy << 8, n0 = bxx << 7;
    const int tid = threadIdx.x, w = tid >> 6, lane = tid & 63;
    const int wm = w >> 1, wn = w & 1;
    const int l15 = lane & 15, lk = lane >> 4;

    floatx4 acc[4][4] = {};

    for (int k0 = 0; k0 < K; k0 += 64) {
        #pragma unroll
        for (int i = 0; i < 4; ++i) {
            int c = 4 * w + i;
            int cg = c >> 1, ckh = c & 1;
            gload16(A + (size_t)(m0 + cg * 16 + l15) * lda + k0 + lk * 8 + ckh * 32,
                    &As[c * 512]);
        }
        #pragma unroll
        for (int i = 0; i < 2; ++i) {
            int c = 2 * w + i;
            int cg = c >> 1, ckh = c & 1;
            gload16(Bt + (size_t)(n0 + cg * 16 + l15) * ldb + k0 + lk * 8 + ckh * 32,
                    &Bs[c * 512]);
        }
        __syncthreads();
        #pragma unroll
        for (int kh = 0; kh < 2; ++kh) {
            bf16x8 af[4], bfr[4];
            #pragma unroll
            for (int mi = 0; mi < 4; ++mi)
                af[mi] = *(const bf16x8*)&As[(((wm * 4 + mi) * 2 + kh) * 64 + lane) * 8];
            #pragma unroll
            for (int ni = 0; ni < 4; ++ni)
                bfr[ni] = *(const bf16x8*)&Bs[(((wn * 4 + ni) * 2 + kh) * 64 + lane) * 8];
            #pragma unroll
            for (int mi = 0; mi < 4; ++mi)
                #pragma unroll
                for (int ni = 0; ni < 4; ++ni)
                    acc[mi][ni] = __builtin_amdgcn_mfma_f32_16x16x32_bf16(
                        af[mi], bfr[ni], acc[mi][ni], 0, 0, 0);
        }
        __syncthreads();
    }

    #pragma unroll
    for (int mi = 0; mi < 4; ++mi)
        #pragma unroll
        for (int ni = 0; ni < 4; ++ni) {
            float bv = bias[n0 + wn * 64 + ni * 16 + l15];
            #pragma unroll
            for (int r = 0; r < 4; ++r) acc[mi][ni][r] += bv;
        }

    #pragma unroll
    for (int mi = 0; mi < 4; ++mi) {
        #pragma unroll
        for (int r = 0; r < 4; ++r) {
            int grow = m0 + wm * 64 + mi * 16 + lk * 4 + r;
            #pragma unroll
            for (int ni = 0; ni < 4; ++ni)
                Cf[(size_t)grow * ldc + n0 + wn * 64 + ni * 16 + l15] = acc[mi][ni][r];
        }
    }

    #pragma unroll
    for (int mi = 0; mi < 4; ++mi) {
        #pragma unroll
        for (int r = 0; r < 4; ++r) {
            float m4 = fmaxf(fmaxf(acc[mi][0][r], acc[mi][1][r]),
                             fmaxf(acc[mi][2][r], acc[mi][3][r]));
            m4 = fmaxf(m4, __shfl_xor(m4, 1));
            m4 = fmaxf(m4, __shfl_xor(m4, 2));
            m4 = fmaxf(m4, __shfl_xor(m4, 4));
            m4 = fmaxf(m4, __shfl_xor(m4, 8));
            float s4 = 0.f;
            #pragma unroll
            for (int ni = 0; ni < 4; ++ni) s4 += __expf(acc[mi][ni][r] - m4);
            s4 += __shfl_xor(s4, 1);
            s4 += __shfl_xor(s4, 2);
            s4 += __shfl_xor(s4, 4);
            s4 += __shfl_xor(s4, 8);
            if (l15 == 0) {
                int R = wm * 64 + mi * 16 + lk * 4 + r;
                sstat[0][R][wn] = m4;
                sstat[1][R][wn] = s4;
            }
        }
    }
    __syncthreads();
    if (tid < 256) {
        float ma = sstat[0][tid][0], mb = sstat[0][tid][1];
        float M = fmaxf(ma, mb);
        float S = sstat[1][tid][0] * __expf(ma - M)
                + sstat[1][tid][1] * __expf(mb - M);
        smax[(size_t)(m0 + tid) * nblks + bxx] = M;
        ssum[(size_t)(m0 + tid) * nblks + bxx] = S;
    }
}

// ---------------- layer GEMM 128x128: counted-vmcnt double-buffer (T3/T4)
// vt non-null (QKV only): V-region tiles (n0 >= 1024) written TRANSPOSED to vt.
__global__ __launch_bounds__(256, 2)
void mfma_gemm_db(const ushort* __restrict__ A, int lda,
                  const ushort* __restrict__ Bt, int ldb,
                  float* __restrict__ Cf, ushort* __restrict__ Cbf, int ldc,
                  const float* __restrict__ bias,
                  const float* __restrict__ resid, int ldres,
                  int K, int relu, ushort* __restrict__ vt)
{
    __shared__ ushort st[2][2][8192];   // [buf][A|B] = 64 KB

    const int m0 = blockIdx.y << 7, n0 = blockIdx.x << 7;
    const int tid = threadIdx.x, w = tid >> 6, lane = tid & 63;
    const int wm = w >> 1, wn = w & 1;
    const int l15 = lane & 15, lk = lane >> 4;
    const int nt = K >> 6;

    auto STAGE = [&](int t, int p) {
        const int k0 = t << 6;
        #pragma unroll
        for (int i = 0; i < 4; ++i) {
            int c = 4 * w + i;
            int cg = c >> 3, cmi = (c >> 1) & 3, ckh = c & 1;
            gload16(A + (size_t)(m0 + cg * 64 + cmi * 16 + l15) * lda
                      + k0 + lk * 8 + ckh * 32, &st[p][0][c * 512]);
            gload16(Bt + (size_t)(n0 + cg * 64 + cmi * 16 + l15) * ldb
                       + k0 + lk * 8 + ckh * 32, &st[p][1][c * 512]);
        }
    };

    floatx4 acc[4][4] = {};
    STAGE(0, 0);

    for (int t = 0; t < nt; ++t) {
        const int p = t & 1;
        if (t + 1 < nt) {
            STAGE(t + 1, p ^ 1);
            asm volatile("s_waitcnt vmcnt(8)" ::: "memory");
        } else {
            asm volatile("s_waitcnt vmcnt(0)" ::: "memory");
        }
        __builtin_amdgcn_s_barrier();
        __builtin_amdgcn_sched_barrier(0);
        #pragma unroll
        for (int kh = 0; kh < 2; ++kh) {
            bf16x8 af[4], bfr[4];
            #pragma unroll
            for (int mi = 0; mi < 4; ++mi)
                af[mi] = *(const bf16x8*)&st[p][0][((wm * 8 + mi * 2 + kh) * 64 + lane) * 8];
            #pragma unroll
            for (int ni = 0; ni < 4; ++ni)
                bfr[ni] = *(const bf16x8*)&st[p][1][((wn * 8 + ni * 2 + kh) * 64 + lane) * 8];
            #pragma unroll
            for (int mi = 0; mi < 4; ++mi)
                #pragma unroll
                for (int ni = 0; ni < 4; ++ni)
                    acc[mi][ni] = __builtin_amdgcn_mfma_f32_16x16x32_bf16(
                        af[mi], bfr[ni], acc[mi][ni], 0, 0, 0);
        }
        __builtin_amdgcn_sched_barrier(0);
        __builtin_amdgcn_s_barrier();
    }

    #pragma unroll
    for (int mi = 0; mi < 4; ++mi)
        #pragma unroll
        for (int ni = 0; ni < 4; ++ni)
            #pragma unroll
            for (int r = 0; r < 4; ++r) {
                float v = acc[mi][ni][r];
                if (bias) v += bias[n0 + wn * 64 + ni * 16 + l15];
                if (relu) v = fmaxf(v, 0.0f);
                acc[mi][ni][r] = v;
            }

    if (vt && n0 >= 1024) {
        ushort* Ls = &st[0][0][0];          // 128 x 136 staging
        #pragma unroll
        for (int mi = 0; mi < 4; ++mi)
            #pragma unroll
            for (int r = 0; r < 4; ++r) {
                int lrow = wm * 64 + mi * 16 + lk * 4 + r;
                #pragma unroll
                for (int ni = 0; ni < 4; ++ni)
                    Ls[lrow * 136 + wn * 64 + ni * 16 + l15] = f2bf(acc[mi][ni][r]);
            }
        __syncthreads();
        const int b = m0 >> 11, tbase = m0 & 2047;
        const int h0 = (n0 - 1024) >> 6;
        const int dr = tid >> 1;
        const int half = tid & 1;
        const int z = b * HH + h0 + (dr >> 6);
        const int d = dr & 63;
        ushort* dst = vt + ((size_t)z * 64 + d) * TT + tbase + half * 64;
        #pragma unroll
        for (int j = 0; j < 8; ++j) {
            union { ushort u[8]; uint4 v; } pk;
            #pragma unroll
            for (int e = 0; e < 8; ++e)
                pk.u[e] = Ls[(half * 64 + j * 8 + e) * 136 + dr];
            *(uint4*)(dst + j * 8) = pk.v;
        }
        return;
    }

    #pragma unroll
    for (int mi = 0; mi < 4; ++mi) {
        #pragma unroll
        for (int r = 0; r < 4; ++r) {
            int grow = m0 + wm * 64 + mi * 16 + lk * 4 + r;
            #pragma unroll
            for (int ni = 0; ni < 4; ++ni) {
                int gcol = n0 + wn * 64 + ni * 16 + l15;
                float v = acc[mi][ni][r];
                if (resid) v += resid[(size_t)grow * ldres + gcol];
                if (Cbf) Cbf[(size_t)grow * ldc + gcol] = f2bf(v);
                else     Cf [(size_t)grow * ldc + gcol] = v;
            }
        }
    }
}

// ---------------- layer GEMM 64x128 (for N=512 outputs: 256-block grids)
__global__ __launch_bounds__(256, 3)
void mfma_gemm_db64(const ushort* __restrict__ A, int lda,
                    const ushort* __restrict__ Bt, int ldb,
                    float* __restrict__ Cf, ushort* __restrict__ Cbf, int ldc,
                    const float* __restrict__ bias,
                    const float* __restrict__ resid, int ldres,
                    int K, int relu)
{
    __shared__ ushort stA[2][8 * 512];
    __shared__ ushort stB[2][16 * 512];

    const int m0 = blockIdx.y << 6, n0 = blockIdx.x << 7;
    const int tid = threadIdx.x, w = tid >> 6, lane = tid & 63;
    const int l15 = lane & 15, lk = lane >> 4;
    const int nt = K >> 6;

    auto STAGE = [&](int t, int p) {
        const int k0 = t << 6;
        #pragma unroll
        for (int i = 0; i < 2; ++i) {
            int c = 2 * w + i;
            int cmi = c >> 1, ckh = c & 1;
            gload16(A + (size_t)(m0 + cmi * 16 + l15) * lda
                      + k0 + lk * 8 + ckh * 32, &stA[p][c * 512]);
        }
        #pragma unroll
        for (int i = 0; i < 4; ++i) {
            int c = 4 * w + i;
            int cnj = c >> 1, ckh = c & 1;
            gload16(Bt + (size_t)(n0 + cnj * 16 + l15) * ldb
                       + k0 + lk * 8 + ckh * 32, &stB[p][c * 512]);
        }
    };

    floatx4 acc[4][2] = {};
    STAGE(0, 0);

    for (int t = 0; t < nt; ++t) {
        const int p = t & 1;
        if (t + 1 < nt) {
            STAGE(t + 1, p ^ 1);
            asm volatile("s_waitcnt vmcnt(6)" ::: "memory");
        } else {
            asm volatile("s_waitcnt vmcnt(0)" ::: "memory");
        }
        __builtin_amdgcn_s_barrier();
        __builtin_amdgcn_sched_barrier(0);
        #pragma unroll
        for (int kh = 0; kh < 2; ++kh) {
            bf16x8 af[4], bfr[2];
            #pragma unroll
            for (int mi = 0; mi < 4; ++mi)
                af[mi] = *(const bf16x8*)&stA[p][((mi * 2 + kh) * 64 + lane) * 8];
            #pragma unroll
            for (int ni = 0; ni < 2; ++ni)
                bfr[ni] = *(const bf16x8*)&stB[p][(((w * 2 + ni) * 2 + kh) * 64 + lane) * 8];
            #pragma unroll
            for (int mi = 0; mi < 4; ++mi)
                #pragma unroll
                for (int ni = 0; ni < 2; ++ni)
                    acc[mi][ni] = __builtin_amdgcn_mfma_f32_16x16x32_bf16(
                        af[mi], bfr[ni], acc[mi][ni], 0, 0, 0);
        }
        __builtin_amdgcn_sched_barrier(0);
        __builtin_amdgcn_s_barrier();
    }

    #pragma unroll
    for (int mi = 0; mi < 4; ++mi)
        #pragma unroll
        for (int ni = 0; ni < 2; ++ni)
            #pragma unroll
            for (int r = 0; r < 4; ++r) {
                float v = acc[mi][ni][r];
                if (bias) v += bias[n0 + w * 32 + ni * 16 + l15];
                if (relu) v = fmaxf(v, 0.0f);
                acc[mi][ni][r] = v;
            }

    #pragma unroll
    for (int mi = 0; mi < 4; ++mi) {
        #pragma unroll
        for (int r = 0; r < 4; ++r) {
            int grow = m0 + mi * 16 + lk * 4 + r;
            #pragma unroll
            for (int ni = 0; ni < 2; ++ni) {
                int gcol = n0 + w * 32 + ni * 16 + l15;
                float v = acc[mi][ni][r];
                if (resid) v += resid[(size_t)grow * ldres + gcol];
                if (Cbf) Cbf[(size_t)grow * ldc + gcol] = f2bf(v);
                else     Cf [(size_t)grow * ldc + gcol] = v;
            }
        }
    }
}

// ---------------- MFMA flash attention, paired q-tiles for load balance
// Block i processes q-tiles i and 31-i -> uniform 33 tile-units per block.
__global__ __launch_bounds__(256)
void attn_mfma_kernel(const ushort* __restrict__ qkv, const ushort* __restrict__ vt,
                      ushort* __restrict__ out)
{
    __shared__ ushort Vl[64 * 64];   // [d][key] linear, swizzled content (8 KB)
    __shared__ ushort Pl[64][72];    // P[q_local][key]

    const int z = blockIdx.y, b = z >> 3, h = z & 7;
    const int pairi = blockIdx.x;    // 0..15
    const int tid = threadIdx.x;
    const int w = tid >> 6, lane = tid & 63;
    const int l15 = lane & 15, g = lane >> 4;
    const float scale = 0.04419417382415922f;  // 1/sqrt(512)
    const ushort* vbase = vt + (size_t)z * 64 * TT;

    for (int pass = 0; pass < 2; ++pass) {
        const int qi = pass == 0 ? pairi : (31 - pairi);
        const int q0 = qi << 6;

        bf16x8 qf0, qf1;
        {
            const ushort* qp = qkv + ((size_t)(b * TT + q0 + 16 * w + l15)) * 1536
                                   + h * HSS + g * 8;
            qf0 = *(const bf16x8*)qp;
            qf1 = *(const bf16x8*)(qp + 32);
        }

        bf16x8 kc[8], kn[8];
        #pragma unroll
        for (int kb = 0; kb < 4; ++kb) {
            const ushort* kp = qkv + ((size_t)(b * TT + kb * 16 + l15)) * 1536
                                   + 512 + h * HSS + g * 8;
            kc[kb * 2]     = *(const bf16x8*)kp;
            kc[kb * 2 + 1] = *(const bf16x8*)(kp + 32);
        }

        floatx4 acc_o[4] = {};
        float lreg[4] = {};

        for (int s0 = 0; s0 <= q0; s0 += 64) {
            __syncthreads();   // prior PV reads (incl. previous pass) done
            #pragma unroll
            for (int i = 0; i < 2; ++i) {
                const int cbase = (w * 2 + i) * 64;
                const int c = cbase + lane;
                const int row = c >> 3;
                const int kg = (c & 7) ^ (row & 7);
                gload16(vbase + (size_t)row * TT + s0 + kg * 8, &Vl[cbase * 8]);
            }

            floatx4 s4[4] = {};
            #pragma unroll
            for (int kb = 0; kb < 4; ++kb) {
                s4[kb] = __builtin_amdgcn_mfma_f32_16x16x32_bf16(qf0, kc[kb*2],   s4[kb], 0, 0, 0);
                s4[kb] = __builtin_amdgcn_mfma_f32_16x16x32_bf16(qf1, kc[kb*2+1], s4[kb], 0, 0, 0);
            }

            const bool more = (s0 + 64 <= q0);
            if (more) {
                #pragma unroll
                for (int kb = 0; kb < 4; ++kb) {
                    const ushort* kp = qkv + ((size_t)(b * TT + s0 + 64 + kb * 16 + l15)) * 1536
                                           + 512 + h * HSS + g * 8;
                    kn[kb * 2]     = *(const bf16x8*)kp;
                    kn[kb * 2 + 1] = *(const bf16x8*)(kp + 32);
                }
            }

            const bool diag = (s0 == q0);
            #pragma unroll
            for (int r = 0; r < 4; ++r) {
                const int qrow = q0 + 16 * w + g * 4 + r;
                #pragma unroll
                for (int kb = 0; kb < 4; ++kb) {
                    float xs = s4[kb][r] * scale;
                    if (diag && (s0 + kb * 16 + l15) > qrow) xs = -1e30f;
                    float p = __expf(xs);
                    lreg[r] += p;
                    Pl[16 * w + g * 4 + r][kb * 16 + l15] = f2bf(p);
                }
            }
            __syncthreads();   // drains V gloads (vmcnt) + Pl writes

            bf16x8 pa0 = *(const bf16x8*)&Pl[16 * w + l15][g * 8];
            bf16x8 pa1 = *(const bf16x8*)&Pl[16 * w + l15][g * 8 + 32];
            #pragma unroll
            for (int db = 0; db < 4; ++db) {
                const int row = db * 16 + l15;
                const bf16x8 vb0 = *(const bf16x8*)&Vl[row * 64 + ((g       ^ (row & 7)) * 8)];
                const bf16x8 vb1 = *(const bf16x8*)&Vl[row * 64 + (((g + 4) ^ (row & 7)) * 8)];
                acc_o[db] = __builtin_amdgcn_mfma_f32_16x16x32_bf16(pa0, vb0, acc_o[db], 0, 0, 0);
                acc_o[db] = __builtin_amdgcn_mfma_f32_16x16x32_bf16(pa1, vb1, acc_o[db], 0, 0, 0);
            }

            if (more) {
                #pragma unroll
                for (int i = 0; i < 8; ++i) kc[i] = kn[i];
            }
        }

        #pragma unroll
        for (int r = 0; r < 4; ++r) {
            float l = lreg[r];
            l += __shfl_xor(l, 1);
            l += __shfl_xor(l, 2);
            l += __shfl_xor(l, 4);
            l += __shfl_xor(l, 8);
            float inv = 1.0f / l;
            ushort* op = out + ((size_t)(b * TT + q0 + 16 * w + g * 4 + r)) * DD + h * HSS;
            #pragma unroll
            for (int db = 0; db < 4; ++db)
                op[db * 16 + l15] = f2bf(acc_o[db][r] * inv);
        }
    }
}

// ---------------- combine per-block softmax partials into per-row loss
__global__ __launch_bounds__(256)
void rowloss_finalize(const float* __restrict__ logits, const int* __restrict__ targets,
                      const float* __restrict__ smax, const float* __restrict__ ssum,
                      float* __restrict__ rowloss)
{
    const int wv = threadIdx.x >> 6, lane = threadIdx.x & 63;
    const int row = blockIdx.x * 4 + wv;
    const float* mrow = smax + (size_t)row * NBLK_V;
    const float* srow = ssum + (size_t)row * NBLK_V;
    float M = -1e30f;
    for (int i = lane; i < NBLK_V; i += 64) M = fmaxf(M, mrow[i]);
    #pragma unroll
    for (int off = 32; off; off >>= 1) M = fmaxf(M, __shfl_xor(M, off));
    float S = 0.f;
    for (int i = lane; i < NBLK_V; i += 64) S += srow[i] * __expf(mrow[i] - M);
    #pragma unroll
    for (int off = 32; off; off >>= 1) S += __shfl_xor(S, off);
    if (lane == 0)
        rowloss[row] = -(logits[(size_t)row * VV + targets[row]] - M - logf(S));
}

__global__ __launch_bounds__(256)
void loss_finalize(const float* __restrict__ rowloss, float* __restrict__ out)
{
    __shared__ float red[256];
    float s = 0.f;
    for (int i = threadIdx.x; i < BB * TT; i += 256) s += rowloss[i];
    red[threadIdx.x] = s; __syncthreads();
    for (int s2 = 128; s2; s2 >>= 1) {
        if (threadIdx.x < s2) red[threadIdx.x] += red[threadIdx.x + s2];
        __syncthreads();
    }
    if (threadIdx.x == 0) out[0] = red[0] * (1.0f / (BB * TT));
}

extern "C" void kernel_launch(void* const* d_in, const int* in_sizes, int n_in,
                              void* d_out, int out_size, void* d_ws, size_t ws_size,
                              hipStream_t stream) {
    const int*   idx     = (const int*)  d_in[0];
    const int*   targets = (const int*)  d_in[1];
    const float* tok_emb = (const float*)d_in[2];
    const float* pos_emb = (const float*)d_in[3];
    const float* ln1_g   = (const float*)d_in[4];
    const float* ln1_b   = (const float*)d_in[5];
    const float* Wq      = (const float*)d_in[6];
    const float* Wk      = (const float*)d_in[7];
    const float* Wv      = (const float*)d_in[8];
    const float* Wo      = (const float*)d_in[9];
    const float* bo      = (const float*)d_in[10];
    const float* ln2_g   = (const float*)d_in[11];
    const float* ln2_b   = (const float*)d_in[12];
    const float* W1      = (const float*)d_in[13];
    const float* b1      = (const float*)d_in[14];
    const float* W2      = (const float*)d_in[15];
    const float* b2      = (const float*)d_in[16];
    const float* lnf_g   = (const float*)d_in[17];
    const float* lnf_b   = (const float*)d_in[18];
    const float* Wout    = (const float*)d_in[19];
    const float* bout    = (const float*)d_in[20];

    float* outf   = (float*)d_out;
    float* logits = outf + 1;                   // [B*T, V] fp32

    const size_t ROW = (size_t)BB * TT;         // 4096

    // ---- d_ws: x (fp32) | h_bf | Wout^T (bf16) | rowloss
    float*  x     = (float*)d_ws;
    ushort* h_bf  = (ushort*)(x + ROW * DD);
    ushort* Woutt = h_bf + ROW * DD;
    float*  rowloss = (float*)(Woutt + (size_t)VV * DD);
    float* smax = x;                            // ROW * NBLK_V (x dead by then)
    float* ssum = x + ROW * NBLK_V;

    // ---- scratch inside the (dead-until-final) logits region of d_out
    ushort* sc     = (ushort*)(outf + 8);
    ushort* qkv_bf = sc;                        // ROW*1536
    ushort* ff_bf  = qkv_bf + ROW * 1536;       // ROW*2048
    ushort* Wqkvt  = ff_bf + ROW * FF_;         // L*1536*512
    ushort* Wot    = Wqkvt + (size_t)LL * 1536 * DD;
    ushort* W1t    = Wot   + (size_t)LL * DD * DD;
    ushort* W2t    = W1t   + (size_t)LL * FF_ * DD;
    ushort* vt_g   = W2t   + (size_t)LL * DD * FF_;   // BB*HH*64*TT (4.2 MB)

    qkv_transpose<<<dim3(8, 96), 256, 0, stream>>>(Wq, Wk, Wv, Wqkvt);
    transpose_cvt<<<dim3(8, 8, LL),  256, 0, stream>>>(Wo,   Wot,   DD,  DD,  (long)DD*DD,   (long)DD*DD);
    transpose_cvt<<<dim3(32, 8, LL), 256, 0, stream>>>(W1,   W1t,   FF_, DD,  (long)DD*FF_,  (long)DD*FF_);
    transpose_cvt<<<dim3(8, 32, LL), 256, 0, stream>>>(W2,   W2t,   DD,  FF_, (long)FF_*DD,  (long)FF_*DD);
    transpose_cvt<<<dim3(500, 8, 1), 256, 0, stream>>>(Wout, Woutt, VV,  DD,  0, 0);

    embed_kernel<<<ROW, 64, 0, stream>>>(idx, tok_emb, pos_emb, x);

    for (int l = 0; l < LL; ++l) {
        ln_kernel<<<ROW / 4, 256, 0, stream>>>(x, ln1_g + l * DD, ln1_b + l * DD, h_bf);

        mfma_gemm_db<<<dim3(1536 / 128, ROW / 128), 256, 0, stream>>>(
            h_bf, DD, Wqkvt + (size_t)l * 1536 * DD, DD,
            nullptr, qkv_bf, 1536, nullptr, nullptr, 0, DD, 0, vt_g);

        // paired q-tiles: 16 pairs x 16 bh = 256 uniformly-loaded blocks
        attn_mfma_kernel<<<dim3(TT / 128, BB * HH), 256, 0, stream>>>(qkv_bf, vt_g, h_bf);

        mfma_gemm_db64<<<dim3(DD / 128, ROW / 64), 256, 0, stream>>>(
            h_bf, DD, Wot + (size_t)l * DD * DD, DD,
            x, nullptr, DD, bo + l * DD, x, DD, DD, 0);

        ln_kernel<<<ROW / 4, 256, 0, stream>>>(x, ln2_g + l * DD, ln2_b + l * DD, h_bf);

        mfma_gemm_db<<<dim3(FF_ / 128, ROW / 128), 256, 0, stream>>>(
            h_bf, DD, W1t + (size_t)l * FF_ * DD, DD,
            nullptr, ff_bf, FF_, b1 + l * FF_, nullptr, 0, DD, 1, nullptr);

        mfma_gemm_db64<<<dim3(DD / 128, ROW / 64), 256, 0, stream>>>(
            ff_bf, FF_, W2t + (size_t)l * DD * FF_, FF_,
            x, nullptr, DD, b2 + l * DD, x, DD, FF_, 0);
    }

    ln_kernel<<<ROW / 4, 256, 0, stream>>>(x, lnf_g, lnf_b, h_bf);

    mfma_gemm_logits<<<dim3(VV / 128, ROW / 256), 512, 0, stream>>>(
        h_bf, DD, Woutt, DD,
        logits, VV, bout, DD,
        smax, ssum, NBLK_V);

    rowloss_finalize<<<ROW / 4, 256, 0, stream>>>(logits, targets, smax, ssum, rowloss);
    loss_finalize<<<1, 256, 0, stream>>>(rowloss, outf);
}